// Round 5
// baseline (350.683 us; speedup 1.0000x reference)
//
#include <hip/hip_runtime.h>

#define N_TOK 2048
#define DMODEL 1024
#define NH 16
#define NKV 4
#define HDIM 64
#define SCALE_LOG2E 0.1803368801111204f  // (1/8) * log2(e)
#define NBLK 512

typedef __attribute__((ext_vector_type(8))) short short8;
typedef __attribute__((ext_vector_type(4))) float f32x4;
typedef __attribute__((ext_vector_type(16))) float f32x16;
typedef unsigned short u16;
typedef unsigned int u32;

__device__ __forceinline__ u16 f2bf(float x) {
    u32 u = __float_as_uint(x);
    u += 0x7FFF + ((u >> 16) & 1);   // round-to-nearest-even
    return (u16)(u >> 16);
}
__device__ __forceinline__ u32 pack2(float a, float b) {
    return (u32)f2bf(a) | ((u32)f2bf(b) << 16);
}
// pack high halves (truncating bf16) of two floats: [bf(a) | bf(b)<<16]
__device__ __forceinline__ u32 pack2t(float a, float b) {
    return __builtin_amdgcn_perm(__float_as_uint(b), __float_as_uint(a), 0x07060302u);
}

// ---------------------------------------------------------------------------
// Grid-wide barrier, all NBLK blocks resident (512 = 2 blocks/CU x 256 CU).
// Release fence (L2 writeback) -> agent-scope rendezvous -> acquire fence
// (L1/L2 invalidate). Generation counter, no per-barrier state reset needed.
// ---------------------------------------------------------------------------
__device__ __forceinline__ void gridbar(u32* cnt, u32* gen) {
    __syncthreads();
    if (threadIdx.x == 0) {
        __threadfence();   // release: our stores reach device scope
        u32 g = __hip_atomic_load(gen, __ATOMIC_RELAXED, __HIP_MEMORY_SCOPE_AGENT);
        if (__hip_atomic_fetch_add(cnt, 1u, __ATOMIC_ACQ_REL, __HIP_MEMORY_SCOPE_AGENT)
            == (u32)(NBLK - 1)) {
            __hip_atomic_store(cnt, 0u, __ATOMIC_RELAXED, __HIP_MEMORY_SCOPE_AGENT);
            __hip_atomic_fetch_add(gen, 1u, __ATOMIC_RELEASE, __HIP_MEMORY_SCOPE_AGENT);
        } else {
            while (__hip_atomic_load(gen, __ATOMIC_RELAXED, __HIP_MEMORY_SCOPE_AGENT) == g)
                __builtin_amdgcn_s_sleep(2);
        }
        __threadfence();   // acquire: invalidate caches before reading others' data
    }
    __syncthreads();
}

// ---------------------------------------------------------------------------
// ONE persistent kernel, 4 phases separated by grid barriers.
// Phase 0: prep (x->bf16, W transposes)       896 jobs / 512 blocks
// Phase 1: QKV GEMM 128x64 BK=64 dbuf         384 jobs (128 blocks idle)
// Phase 2: attn 32x32x16 in-block key-split   512 jobs
// Phase 3: out GEMM 64x64 BK=64 dbuf          512 jobs
// Phase bodies identical to round-3 kernels (blockIdx -> job index).
// ---------------------------------------------------------------------------
__global__ __launch_bounds__(256, 2) void fused(
    const float* __restrict__ x, const float* __restrict__ fc, const float* __restrict__ fs,
    const float* __restrict__ Wq, const float* __restrict__ Wk,
    const float* __restrict__ Wv, const float* __restrict__ Wo,
    u16* __restrict__ xb, u16* __restrict__ Wqt, u16* __restrict__ Wkt,
    u16* __restrict__ Wvt, u16* __restrict__ Wot,
    u16* __restrict__ qb, u16* __restrict__ kb, u16* __restrict__ fv,
    u16* __restrict__ aob, float* __restrict__ out, u32* __restrict__ sync)
{
    __shared__ __align__(16) unsigned char smem[55296];
    const int b = blockIdx.x;
    const int t = threadIdx.x;

    // ===================== phase 0: prep =====================
    for (int job = b; job < 896; job += NBLK) {
        if (job < 256) {
            size_t base = (size_t)job * 8192;
#pragma unroll
            for (int i = 0; i < 8; ++i) {
                float4 v = *(const float4*)(x + base + i * 1024 + t * 4);
                uint2 p; p.x = pack2(v.x, v.y); p.y = pack2(v.z, v.w);
                *(uint2*)(xb + base + i * 1024 + t * 4) = p;
            }
        } else {
            const float* W; u16* Wt; int NC, jr;
            if (job < 512)      { W = Wq; Wt = Wqt; NC = 1024; jr = job - 256; }
            else if (job < 768) { W = Wo; Wt = Wot; NC = 1024; jr = job - 512; }
            else if (job < 832) { W = Wk; Wt = Wkt; NC = 256;  jr = job - 768; }
            else                { W = Wv; Wt = Wvt; NC = 256;  jr = job - 832; }
            const int n0 = (NC == 1024 ? (jr & 15) : (jr & 3)) * 64;
            const int k0 = (NC == 1024 ? (jr >> 4) : (jr >> 2)) * 64;
            float (*T)[68] = (float(*)[68])smem;
            const int row = t >> 2, cs = (t & 3) * 16;
#pragma unroll
            for (int i = 0; i < 4; ++i)
                *(float4*)&T[row][cs + i * 4] =
                    *(const float4*)(W + (size_t)(k0 + row) * NC + n0 + cs + i * 4);
            __syncthreads();
            const int nl = t >> 2, ks = (t & 3) * 16;
            u32 pk[8];
#pragma unroll
            for (int i = 0; i < 8; ++i)
                pk[i] = pack2(T[ks + 2 * i][nl], T[ks + 2 * i + 1][nl]);
            u16* dst = Wt + (size_t)(n0 + nl) * DMODEL + k0 + ks;
            uint4 w0; w0.x = pk[0]; w0.y = pk[1]; w0.z = pk[2]; w0.w = pk[3];
            uint4 w1; w1.x = pk[4]; w1.y = pk[5]; w1.z = pk[6]; w1.w = pk[7];
            *(uint4*)(dst) = w0;
            *(uint4*)(dst + 8) = w1;
            __syncthreads();   // T reused by next job iteration
        }
    }
    gridbar(sync, sync + 16);

    // ===================== phase 1: QKV GEMM =====================
    if (b < 384) {
        u16 (*As)[128][72] = (u16(*)[128][72])smem;          // [2][128][72]
        u16 (*Bs)[64][72]  = (u16(*)[64][72])(smem + 36864); // [2][64][72]
        const int m0 = (b & 15) * 128;
        const int by = b >> 4;

        const u16* Bt; int nl0, ep;           // ep: 1 rope bf16, 2 FV2
        u16* dbf = nullptr; int dstride = 0; float epsc = 1.f;
        if (by < 16)      { Bt = Wqt; nl0 = by * 64;        dbf = qb; ep = 1; dstride = 1024;
                            epsc = SCALE_LOG2E; }
        else if (by < 20) { Bt = Wkt; nl0 = (by - 16) * 64; dbf = kb; ep = 1; dstride = 256; }
        else              { Bt = Wvt; nl0 = (by - 20) * 64; ep = 2; }

        const int w = t >> 6, lane = t & 63;
        const int quad = lane >> 4, l15 = lane & 15;
        const int wm = (w >> 1) * 64, wn = (w & 1) * 32;
        const int arow = t >> 1, ac = (t & 1) * 32;     // A stage: 128 rows x 64 cols
        const int brow = t >> 2, bc = (t & 3) * 16;     // B stage: 64 rows x 64 cols

        const u16* Ap = xb + (size_t)(m0 + arow) * DMODEL + ac;
        const u16* Bp = Bt + (size_t)(nl0 + brow) * DMODEL + bc;

        f32x4 acc[4][2];
#pragma unroll
        for (int i = 0; i < 4; ++i)
#pragma unroll
            for (int j = 0; j < 2; ++j) acc[i][j] = {0.f, 0.f, 0.f, 0.f};

        uint4 a_r[4], b_r[2];
#pragma unroll
        for (int ci = 0; ci < 4; ++ci) a_r[ci] = *(const uint4*)(Ap + ci * 8);
        b_r[0] = *(const uint4*)(Bp);
        b_r[1] = *(const uint4*)(Bp + 8);
#pragma unroll
        for (int ci = 0; ci < 4; ++ci) *(uint4*)&As[0][arow][ac + ci * 8] = a_r[ci];
        *(uint4*)&Bs[0][brow][bc]     = b_r[0];
        *(uint4*)&Bs[0][brow][bc + 8] = b_r[1];
        __syncthreads();

        for (int it = 0; it < 16; ++it) {
            const int cur = it & 1;
            const bool more = (it + 1) < 16;
            if (more) {
                const int k1 = (it + 1) * 64;
#pragma unroll
                for (int ci = 0; ci < 4; ++ci) a_r[ci] = *(const uint4*)(Ap + k1 + ci * 8);
                b_r[0] = *(const uint4*)(Bp + k1);
                b_r[1] = *(const uint4*)(Bp + k1 + 8);
            }
#pragma unroll
            for (int c = 0; c < 2; ++c) {
                short8 af[4], bf[2];
#pragma unroll
                for (int i = 0; i < 4; ++i)
                    af[i] = *(const short8*)&As[cur][wm + i * 16 + l15][c * 32 + quad * 8];
#pragma unroll
                for (int j = 0; j < 2; ++j)
                    bf[j] = *(const short8*)&Bs[cur][wn + j * 16 + l15][c * 32 + quad * 8];
#pragma unroll
                for (int i = 0; i < 4; ++i)
#pragma unroll
                    for (int j = 0; j < 2; ++j)
                        acc[i][j] = __builtin_amdgcn_mfma_f32_16x16x32_bf16(af[i], bf[j], acc[i][j], 0, 0, 0);
            }
            if (more) {
                const int nx = cur ^ 1;
#pragma unroll
                for (int ci = 0; ci < 4; ++ci) *(uint4*)&As[nx][arow][ac + ci * 8] = a_r[ci];
                *(uint4*)&Bs[nx][brow][bc]     = b_r[0];
                *(uint4*)&Bs[nx][brow][bc + 8] = b_r[1];
                __syncthreads();
            }
        }

#pragma unroll
        for (int i = 0; i < 4; ++i)
#pragma unroll
            for (int j = 0; j < 2; ++j) {
                const int cl = nl0 + wn + j * 16 + l15;
                if (ep == 1) {
#pragma unroll
                    for (int r4 = 0; r4 < 4; ++r4) {
                        const int r = m0 + wm + i * 16 + quad * 4 + r4;
                        float own = acc[i][j][r4];
                        float other = __shfl_xor(own, 1, 64);
                        const int p = (cl & 63) >> 1;
                        const float c = fc[r * 32 + p] * epsc, s = fs[r * 32 + p] * epsc;
                        float outv = ((cl & 1) == 0) ? (own * c - other * s)
                                                     : (other * s + own * c);
                        dbf[(size_t)r * dstride + cl] = f2bf(outv);
                    }
                } else {
                    // packed 4-key store: r4=0..3 are consecutive jv in FV2
                    const int rb = m0 + wm + i * 16 + quad * 4;
                    const int g = cl >> 6, d = cl & 63;
                    const int d2 = d >> 5, dl = d & 31;
                    const int keyblk = rb >> 7, kg = (rb >> 5) & 3;
                    const int kst = (rb >> 4) & 1, hb = (rb >> 3) & 1, jv = rb & 7;
                    size_t idx = ((((((size_t)(g * 16 + keyblk) * 4 + kg) * 2 + kst) * 2 + d2)
                                   * 2 + hb) * 32 + dl) * 8 + jv;
                    uint2 pk;
                    pk.x = pack2(acc[i][j][0], acc[i][j][1]);
                    pk.y = pack2(acc[i][j][2], acc[i][j][3]);
                    *(uint2*)(fv + idx) = pk;
                }
            }
    }
    gridbar(sync, sync + 16);

    // ===================== phase 2: attention =====================
    {
        u16 (*Ks)[2][64][72] = (u16(*)[2][64][72])smem;        // [2][2][64][72]
        u16 (*Ps)[32][40]    = (u16(*)[32][40])(smem + 36864); // [4][32][40]
        const int n0 = (b & 31) * 64;
        const int h = b >> 5, kvh = h >> 2;
        const int w = t >> 6, lane = t & 63;
        const int hi = lane >> 5, l31 = lane & 31;
        const int qgrp = w & 1, khalf = w >> 1;
        const int srow = t >> 1, ssel = (t & 1) * 32;   // staging: 2x64 rows x 64d
        const int khalf_s = srow >> 6, klocal = srow & 63;

        const short8 ones = {(short)0x3F80, (short)0x3F80, (short)0x3F80, (short)0x3F80,
                             (short)0x3F80, (short)0x3F80, (short)0x3F80, (short)0x3F80};

        // Q B-frags: B[k=d][n=q], q = n0 + qgrp*32 + l31, d = s*16 + hi*8 + j
        const u16* qp = qb + (size_t)(n0 + qgrp * 32 + l31) * (NH * HDIM) + h * HDIM + hi * 8;
        short8 qf[4];
#pragma unroll
        for (int s = 0; s < 4; ++s) qf[s] = *(const short8*)(qp + s * 16);

        const u16* kbase = kb + (size_t)(khalf_s * 1024 + klocal) * (NKV * HDIM) + kvh * HDIM + ssel;
        const u16* fvb = fv + ((size_t)kvh * 16 * 8192) + (size_t)lane * 8;

        f32x16 o[2], o_l;
#pragma unroll
        for (int d2 = 0; d2 < 2; ++d2)
#pragma unroll
            for (int r = 0; r < 16; ++r) o[d2][r] = 0.f;
#pragma unroll
        for (int r = 0; r < 16; ++r) o_l[r] = 0.f;

        // prologue: first 64 keys of each half -> buf 0
#pragma unroll
        for (int c = 0; c < 4; ++c)
            *(uint4*)&Ks[0][khalf_s][klocal][ssel + c * 8] = *(const uint4*)(kbase + c * 8);
        __syncthreads();

        for (int rd = 0; rd < 16; ++rd) {
            const int cur = rd & 1, nxt = cur ^ 1;
            const int rdn = (rd + 1) & 15;            // wrap: dead store on last round
            uint4 kr[4];
#pragma unroll
            for (int c = 0; c < 4; ++c)
                kr[c] = *(const uint4*)(kbase + (size_t)(rdn * 64) * (NKV * HDIM) + c * 8);

#pragma unroll
            for (int kg = 0; kg < 2; ++kg) {
                const int kg_global = khalf * 32 + rd * 2 + kg;   // 32-key group 0..63
                const int keyblk = kg_global >> 2, kgi = kg_global & 3;
                // ---- V frags (global, coalesced; used after softmax) ----
                short8 vf[2][2];
#pragma unroll
                for (int s = 0; s < 2; ++s)
#pragma unroll
                    for (int d2 = 0; d2 < 2; ++d2)
                        vf[s][d2] = *(const short8*)(fvb +
                            ((((size_t)keyblk * 4 + kgi) * 2 + s) * 2 + d2) * 512);
                // ---- S^T = K Q^T over d=64 (4 ksteps of 16) ----
                f32x16 sa;
#pragma unroll
                for (int r = 0; r < 16; ++r) sa[r] = 0.f;
#pragma unroll
                for (int s = 0; s < 4; ++s) {
                    short8 kf = *(const short8*)&Ks[cur][khalf][kg * 32 + l31][s * 16 + hi * 8];
                    sa = __builtin_amdgcn_mfma_f32_32x32x16_bf16(kf, qf[s], sa, 0, 0, 0);
                }
                // ---- p = exp2(s); P -> Ps (key rows (r&3)+8*(r>>2)+4*hi) ----
                float p[16];
#pragma unroll
                for (int r = 0; r < 16; ++r) p[r] = __builtin_amdgcn_exp2f(sa[r]);
#pragma unroll
                for (int blk = 0; blk < 4; ++blk) {
                    uint2 pk;
                    pk.x = pack2t(p[blk * 4 + 0], p[blk * 4 + 1]);
                    pk.y = pack2t(p[blk * 4 + 2], p[blk * 4 + 3]);
                    *(uint2*)&Ps[w][l31][blk * 8 + 4 * hi] = pk;
                }
                const short8 ap0 = *(const short8*)&Ps[w][l31][hi * 8];
                const short8 ap1 = *(const short8*)&Ps[w][l31][16 + hi * 8];
                // ---- O += P V ; l += P 1 (row-sum on the matrix pipe) ----
#pragma unroll
                for (int d2 = 0; d2 < 2; ++d2) {
                    o[d2] = __builtin_amdgcn_mfma_f32_32x32x16_bf16(ap0, vf[0][d2], o[d2], 0, 0, 0);
                    o[d2] = __builtin_amdgcn_mfma_f32_32x32x16_bf16(ap1, vf[1][d2], o[d2], 0, 0, 0);
                }
                o_l = __builtin_amdgcn_mfma_f32_32x32x16_bf16(ap0, ones, o_l, 0, 0, 0);
                o_l = __builtin_amdgcn_mfma_f32_32x32x16_bf16(ap1, ones, o_l, 0, 0, 0);
            }
            // ---- stage next 64-key tiles (both halves); single barrier ----
#pragma unroll
            for (int c = 0; c < 4; ++c)
                *(uint4*)&Ks[nxt][khalf_s][klocal][ssel + c * 8] = kr[c];
            __syncthreads();
        }

        // ---- merge key halves through LDS (reuse Ks) and write bf16 ----
        float* Xf = (float*)smem;   // Ox[2][32][64] (4096 f32) + Lx[64]
        if (khalf == 1) {
#pragma unroll
            for (int d2 = 0; d2 < 2; ++d2)
#pragma unroll
                for (int r = 0; r < 16; ++r) {
                    const int q32 = (r & 3) + 8 * (r >> 2) + 4 * hi;
                    Xf[qgrp * 2048 + q32 * 64 + d2 * 32 + l31] = o[d2][r];
                }
            if (l31 == 0) {
#pragma unroll
                for (int r = 0; r < 16; ++r) {
                    const int q32 = (r & 3) + 8 * (r >> 2) + 4 * hi;
                    Xf[4096 + qgrp * 32 + q32] = o_l[r];
                }
            }
        }
        __syncthreads();
        if (khalf == 0) {
            float linv[16];
#pragma unroll
            for (int r = 0; r < 16; ++r) {
                const int q32 = (r & 3) + 8 * (r >> 2) + 4 * hi;
                linv[r] = 1.f / (o_l[r] + Xf[4096 + qgrp * 32 + q32]);
            }
#pragma unroll
            for (int d2 = 0; d2 < 2; ++d2)
#pragma unroll
                for (int r = 0; r < 16; ++r) {
                    const int q32 = (r & 3) + 8 * (r >> 2) + 4 * hi;
                    const float val = o[d2][r] + Xf[qgrp * 2048 + q32 * 64 + d2 * 32 + l31];
                    const int qrow = n0 + qgrp * 32 + q32;
                    aob[(size_t)qrow * (NH * HDIM) + h * HDIM + d2 * 32 + l31] = f2bf(val * linv[r]);
                }
        }
    }
    gridbar(sync, sync + 16);

    // ===================== phase 3: output GEMM =====================
    {
        u16 (*As)[64][72] = (u16(*)[64][72])smem;            // [2][64][72]
        u16 (*Bs)[64][72] = (u16(*)[64][72])(smem + 18432);  // [2][64][72]
        const int m0 = (b & 31) * 64;
        const int nl0 = (b >> 5) * 64;

        const int w = t >> 6, lane = t & 63;
        const int quad = lane >> 4, l15 = lane & 15;
        const int wm = (w >> 1) * 32, wn = (w & 1) * 32;
        const int srow = t >> 2, sk = (t & 3) * 16;

        const u16* Ap = aob + (size_t)(m0 + srow) * DMODEL + sk;
        const u16* Bp = Wot + (size_t)(nl0 + srow) * DMODEL + sk;

        f32x4 acc[2][2];
#pragma unroll
        for (int i = 0; i < 2; ++i)
#pragma unroll
            for (int j = 0; j < 2; ++j) acc[i][j] = {0.f, 0.f, 0.f, 0.f};

        uint4 a_r[2], b_r[2];
        a_r[0] = *(const uint4*)(Ap);     a_r[1] = *(const uint4*)(Ap + 8);
        b_r[0] = *(const uint4*)(Bp);     b_r[1] = *(const uint4*)(Bp + 8);
        *(uint4*)&As[0][srow][sk]     = a_r[0];
        *(uint4*)&As[0][srow][sk + 8] = a_r[1];
        *(uint4*)&Bs[0][srow][sk]     = b_r[0];
        *(uint4*)&Bs[0][srow][sk + 8] = b_r[1];
        __syncthreads();

        for (int it = 0; it < 16; ++it) {
            const int cur = it & 1;
            const bool more = (it + 1) < 16;
            if (more) {
                const int k1 = (it + 1) * 64;
                a_r[0] = *(const uint4*)(Ap + k1);     a_r[1] = *(const uint4*)(Ap + k1 + 8);
                b_r[0] = *(const uint4*)(Bp + k1);     b_r[1] = *(const uint4*)(Bp + k1 + 8);
            }
#pragma unroll
            for (int c = 0; c < 2; ++c) {
                short8 af[2], bf[2];
#pragma unroll
                for (int i = 0; i < 2; ++i)
                    af[i] = *(const short8*)&As[cur][wm + i * 16 + l15][c * 32 + quad * 8];
#pragma unroll
                for (int j = 0; j < 2; ++j)
                    bf[j] = *(const short8*)&Bs[cur][wn + j * 16 + l15][c * 32 + quad * 8];
#pragma unroll
                for (int i = 0; i < 2; ++i)
#pragma unroll
                    for (int j = 0; j < 2; ++j)
                        acc[i][j] = __builtin_amdgcn_mfma_f32_16x16x32_bf16(af[i], bf[j], acc[i][j], 0, 0, 0);
            }
            if (more) {
                const int nx = cur ^ 1;
                *(uint4*)&As[nx][srow][sk]     = a_r[0];
                *(uint4*)&As[nx][srow][sk + 8] = a_r[1];
                *(uint4*)&Bs[nx][srow][sk]     = b_r[0];
                *(uint4*)&Bs[nx][srow][sk + 8] = b_r[1];
                __syncthreads();
            }
        }

#pragma unroll
        for (int i = 0; i < 2; ++i)
#pragma unroll
            for (int j = 0; j < 2; ++j) {
                const int cl = nl0 + wn + j * 16 + l15;
#pragma unroll
                for (int r4 = 0; r4 < 4; ++r4) {
                    const int r = m0 + wm + i * 16 + quad * 4 + r4;
                    out[(size_t)r * 1024 + cl] = acc[i][j][r4];
                }
            }
    }
}

// ---------------------------------------------------------------------------
extern "C" void kernel_launch(void* const* d_in, const int* in_sizes, int n_in,
                              void* d_out, int out_size, void* d_ws, size_t ws_size,
                              hipStream_t stream) {
    const float* x  = (const float*)d_in[0];
    const float* fc = (const float*)d_in[1];
    const float* fs = (const float*)d_in[2];
    const float* Wq = (const float*)d_in[3];
    const float* Wk = (const float*)d_in[4];
    const float* Wv = (const float*)d_in[5];
    const float* Wo = (const float*)d_in[6];
    float* out = (float*)d_out;

    u16* ws  = (u16*)d_ws;
    u16* xb  = ws;                         // 2048*1024
    u16* Wqt = xb  + (size_t)2048 * 1024;  // 1024*1024
    u16* Wkt = Wqt + (size_t)1024 * 1024;  // 256*1024
    u16* Wvt = Wkt + (size_t)256 * 1024;   // 256*1024
    u16* Wot = Wvt + (size_t)256 * 1024;   // 1024*1024
    u16* qb  = Wot + (size_t)1024 * 1024;  // 2048*1024
    u16* kb  = qb  + (size_t)2048 * 1024;  // 2048*256
    u16* fv  = kb  + (size_t)2048 * 256;   // 256*2048 (fragment-packed V, 32-wide)
    u16* aob = fv  + (size_t)256 * 2048;   // 2048*1024
    u32* sync = (u32*)(aob + (size_t)2048 * 1024);  // [cnt, pad..., gen, pad...]

    hipMemsetAsync(sync, 0, 128, stream);
    fused<<<dim3(NBLK), dim3(256), 0, stream>>>(x, fc, fs, Wq, Wk, Wv, Wo,
                                                xb, Wqt, Wkt, Wvt, Wot,
                                                qb, kb, fv, aob, out, sync);
}

// Round 6
// 162.535 us; speedup vs baseline: 2.1576x; 2.1576x over previous
//
#include <hip/hip_runtime.h>

#define N_TOK 2048
#define DMODEL 1024
#define NH 16
#define NKV 4
#define HDIM 64
#define SCALE_LOG2E 0.1803368801111204f  // (1/8) * log2(e)

typedef __attribute__((ext_vector_type(8))) short short8;
typedef __attribute__((ext_vector_type(4))) float f32x4;
typedef __attribute__((ext_vector_type(16))) float f32x16;
typedef unsigned short u16;
typedef unsigned int u32;

__device__ __forceinline__ u16 f2bf(float x) {
    u32 u = __float_as_uint(x);
    u += 0x7FFF + ((u >> 16) & 1);   // round-to-nearest-even
    return (u16)(u >> 16);
}
__device__ __forceinline__ u32 pack2(float a, float b) {
    return (u32)f2bf(a) | ((u32)f2bf(b) << 16);
}
// pack high halves (truncating bf16) of two floats: [bf(a) | bf(b)<<16]
__device__ __forceinline__ u32 pack2t(float a, float b) {
    return __builtin_amdgcn_perm(__float_as_uint(b), __float_as_uint(a), 0x07060302u);
}

// ---------------------------------------------------------------------------
// prep: z=0..3 transpose W (K x NC) -> Wt (NC x K) bf16.
// (x->bf16 conversion folded into gemm_qkv A-staging; z=4 pass removed.)
// ---------------------------------------------------------------------------
__global__ __launch_bounds__(256) void prep(
    const float* __restrict__ Wq, const float* __restrict__ Wk,
    const float* __restrict__ Wv, const float* __restrict__ Wo,
    u16* __restrict__ Wqt, u16* __restrict__ Wkt, u16* __restrict__ Wvt,
    u16* __restrict__ Wot)
{
    const int z = blockIdx.z;
    const int t = threadIdx.x;
    const float* W; u16* Wt; int NC;
    if      (z == 0) { W = Wq; Wt = Wqt; NC = 1024; }
    else if (z == 1) { W = Wk; Wt = Wkt; NC = 256; }
    else if (z == 2) { W = Wv; Wt = Wvt; NC = 256; }
    else             { W = Wo; Wt = Wot; NC = 1024; }
    const int n0 = blockIdx.x * 64;
    if (n0 >= NC) return;
    const int k0 = blockIdx.y * 64;
    __shared__ float T[64][68];
    const int row = t >> 2, cs = (t & 3) * 16;
#pragma unroll
    for (int i = 0; i < 4; ++i)
        *(float4*)&T[row][cs + i * 4] =
            *(const float4*)(W + (size_t)(k0 + row) * NC + n0 + cs + i * 4);
    __syncthreads();
    const int nl = t >> 2, ks = (t & 3) * 16;
    u32 pk[8];
#pragma unroll
    for (int i = 0; i < 8; ++i)
        pk[i] = pack2(T[ks + 2 * i][nl], T[ks + 2 * i + 1][nl]);
    u16* dst = Wt + (size_t)(n0 + nl) * DMODEL + k0 + ks;
    uint4 w0; w0.x = pk[0]; w0.y = pk[1]; w0.z = pk[2]; w0.w = pk[3];
    uint4 w1; w1.x = pk[4]; w1.y = pk[5]; w1.z = pk[6]; w1.w = pk[7];
    *(uint4*)(dst) = w0;
    *(uint4*)(dst + 8) = w1;
}

// ---------------------------------------------------------------------------
// QKV GEMM: tile 128x64, BK=64, double-buffered LDS, ONE barrier per K-iter.
// A staged DIRECTLY from f32 x (RNE-converted during LDS write; bit-identical
// to the old prep pass). 4 waves of 64x32, grid (16,24) = 384.
// by<16 -> Q (rope, x SCALE_LOG2E); 16..19 -> K (rope); 20..23 -> V in
// 32-wide fragment-packed layout FV2 (for mfma_32x32x16 B-operands):
//   FV2[((((((g*16+keyblk)*4+kg)*2+kstep)*2+dgrp)*2+hi)*32+dl)*8+j]
//     = V[key = keyblk*128 + kg*32 + kstep*16 + hi*8 + j][d = dgrp*32 + dl]
// ---------------------------------------------------------------------------
__global__ __launch_bounds__(256, 2) void gemm_qkv(
    const float* __restrict__ xf,
    const u16* __restrict__ B0, const u16* __restrict__ B1, const u16* __restrict__ B2,
    u16* __restrict__ D0, u16* __restrict__ D1, u16* __restrict__ FVout,
    const float* __restrict__ fc, const float* __restrict__ fs)
{
    __shared__ u16 As[2][128][72];
    __shared__ u16 Bs[2][64][72];
    const int t = threadIdx.x;
    const int m0 = blockIdx.x * 128;
    const int by = blockIdx.y;

    const u16* Bt; int nl0, ep;           // ep: 1 rope bf16, 2 FV2
    u16* dbf = nullptr; int dstride = 0; float epsc = 1.f;
    if (by < 16)      { Bt = B0; nl0 = by * 64;        dbf = D0; ep = 1; dstride = 1024;
                        epsc = SCALE_LOG2E; }
    else if (by < 20) { Bt = B1; nl0 = (by - 16) * 64; dbf = D1; ep = 1; dstride = 256; }
    else              { Bt = B2; nl0 = (by - 20) * 64; ep = 2; }

    const int w = t >> 6, lane = t & 63;
    const int quad = lane >> 4, l15 = lane & 15;
    const int wm = (w >> 1) * 64, wn = (w & 1) * 32;
    const int arow = t >> 1, ac = (t & 1) * 32;     // A stage: 128 rows x 64 cols
    const int brow = t >> 2, bc = (t & 3) * 16;     // B stage: 64 rows x 64 cols

    const float* Ap = xf + (size_t)(m0 + arow) * DMODEL + ac;
    const u16* Bp = Bt + (size_t)(nl0 + brow) * DMODEL + bc;

    f32x4 acc[4][2];
#pragma unroll
    for (int i = 0; i < 4; ++i)
#pragma unroll
        for (int j = 0; j < 2; ++j) acc[i][j] = {0.f, 0.f, 0.f, 0.f};

    float4 a_rf[8]; uint4 b_r[2];
#pragma unroll
    for (int ci = 0; ci < 8; ++ci) a_rf[ci] = *(const float4*)(Ap + ci * 4);
    b_r[0] = *(const uint4*)(Bp);
    b_r[1] = *(const uint4*)(Bp + 8);
#pragma unroll
    for (int ci = 0; ci < 4; ++ci) {
        uint4 wv;
        wv.x = pack2(a_rf[2 * ci].x,     a_rf[2 * ci].y);
        wv.y = pack2(a_rf[2 * ci].z,     a_rf[2 * ci].w);
        wv.z = pack2(a_rf[2 * ci + 1].x, a_rf[2 * ci + 1].y);
        wv.w = pack2(a_rf[2 * ci + 1].z, a_rf[2 * ci + 1].w);
        *(uint4*)&As[0][arow][ac + ci * 8] = wv;
    }
    *(uint4*)&Bs[0][brow][bc]     = b_r[0];
    *(uint4*)&Bs[0][brow][bc + 8] = b_r[1];
    __syncthreads();

    for (int it = 0; it < 16; ++it) {
        const int cur = it & 1;
        const bool more = (it + 1) < 16;
        if (more) {
            const int k1 = (it + 1) * 64;
#pragma unroll
            for (int ci = 0; ci < 8; ++ci) a_rf[ci] = *(const float4*)(Ap + k1 + ci * 4);
            b_r[0] = *(const uint4*)(Bp + k1);
            b_r[1] = *(const uint4*)(Bp + k1 + 8);
        }
#pragma unroll
        for (int c = 0; c < 2; ++c) {
            short8 af[4], bf[2];
#pragma unroll
            for (int i = 0; i < 4; ++i)
                af[i] = *(const short8*)&As[cur][wm + i * 16 + l15][c * 32 + quad * 8];
#pragma unroll
            for (int j = 0; j < 2; ++j)
                bf[j] = *(const short8*)&Bs[cur][wn + j * 16 + l15][c * 32 + quad * 8];
#pragma unroll
            for (int i = 0; i < 4; ++i)
#pragma unroll
                for (int j = 0; j < 2; ++j)
                    acc[i][j] = __builtin_amdgcn_mfma_f32_16x16x32_bf16(af[i], bf[j], acc[i][j], 0, 0, 0);
        }
        if (more) {
            const int nx = cur ^ 1;
#pragma unroll
            for (int ci = 0; ci < 4; ++ci) {
                uint4 wv;
                wv.x = pack2(a_rf[2 * ci].x,     a_rf[2 * ci].y);
                wv.y = pack2(a_rf[2 * ci].z,     a_rf[2 * ci].w);
                wv.z = pack2(a_rf[2 * ci + 1].x, a_rf[2 * ci + 1].y);
                wv.w = pack2(a_rf[2 * ci + 1].z, a_rf[2 * ci + 1].w);
                *(uint4*)&As[nx][arow][ac + ci * 8] = wv;
            }
            *(uint4*)&Bs[nx][brow][bc]     = b_r[0];
            *(uint4*)&Bs[nx][brow][bc + 8] = b_r[1];
            __syncthreads();
        }
    }

#pragma unroll
    for (int i = 0; i < 4; ++i)
#pragma unroll
        for (int j = 0; j < 2; ++j) {
            const int cl = nl0 + wn + j * 16 + l15;
            if (ep == 1) {
#pragma unroll
                for (int r4 = 0; r4 < 4; ++r4) {
                    const int r = m0 + wm + i * 16 + quad * 4 + r4;
                    float own = acc[i][j][r4];
                    float other = __shfl_xor(own, 1, 64);
                    const int p = (cl & 63) >> 1;
                    const float c = fc[r * 32 + p] * epsc, s = fs[r * 32 + p] * epsc;
                    float outv = ((cl & 1) == 0) ? (own * c - other * s)
                                                 : (other * s + own * c);
                    dbf[(size_t)r * dstride + cl] = f2bf(outv);
                }
            } else {
                // packed 4-key store: r4=0..3 are consecutive jv in FV2
                const int rb = m0 + wm + i * 16 + quad * 4;
                const int g = cl >> 6, d = cl & 63;
                const int d2 = d >> 5, dl = d & 31;
                const int keyblk = rb >> 7, kg = (rb >> 5) & 3;
                const int kst = (rb >> 4) & 1, hb = (rb >> 3) & 1, jv = rb & 7;
                size_t idx = ((((((size_t)(g * 16 + keyblk) * 4 + kg) * 2 + kst) * 2 + d2)
                               * 2 + hb) * 32 + dl) * 8 + jv;
                uint2 pk;
                pk.x = pack2(acc[i][j][0], acc[i][j][1]);
                pk.y = pack2(acc[i][j][2], acc[i][j][3]);
                *(uint2*)(FVout + idx) = pk;
            }
        }
}

// ---------------------------------------------------------------------------
// Output GEMM: tile 64x64, BK=64, dbuf single-barrier, 4 waves of 32x32,
// fp32 out. grid (32,16) = 512 blocks -> 2 blocks/CU even.
// ---------------------------------------------------------------------------
__global__ __launch_bounds__(256, 2) void gemm_out(
    const u16* __restrict__ A, const u16* __restrict__ Bt, float* __restrict__ Dout)
{
    __shared__ u16 As[2][64][72];
    __shared__ u16 Bs[2][64][72];
    const int t = threadIdx.x;
    const int m0 = blockIdx.x * 64;
    const int nl0 = blockIdx.y * 64;

    const int w = t >> 6, lane = t & 63;
    const int quad = lane >> 4, l15 = lane & 15;
    const int wm = (w >> 1) * 32, wn = (w & 1) * 32;
    const int srow = t >> 2, sk = (t & 3) * 16;

    const u16* Ap = A + (size_t)(m0 + srow) * DMODEL + sk;
    const u16* Bp = Bt + (size_t)(nl0 + srow) * DMODEL + sk;

    f32x4 acc[2][2];
#pragma unroll
    for (int i = 0; i < 2; ++i)
#pragma unroll
        for (int j = 0; j < 2; ++j) acc[i][j] = {0.f, 0.f, 0.f, 0.f};

    uint4 a_r[2], b_r[2];
    a_r[0] = *(const uint4*)(Ap);     a_r[1] = *(const uint4*)(Ap + 8);
    b_r[0] = *(const uint4*)(Bp);     b_r[1] = *(const uint4*)(Bp + 8);
    *(uint4*)&As[0][srow][sk]     = a_r[0];
    *(uint4*)&As[0][srow][sk + 8] = a_r[1];
    *(uint4*)&Bs[0][srow][sk]     = b_r[0];
    *(uint4*)&Bs[0][srow][sk + 8] = b_r[1];
    __syncthreads();

    for (int it = 0; it < 16; ++it) {
        const int cur = it & 1;
        const bool more = (it + 1) < 16;
        if (more) {
            const int k1 = (it + 1) * 64;
            a_r[0] = *(const uint4*)(Ap + k1);     a_r[1] = *(const uint4*)(Ap + k1 + 8);
            b_r[0] = *(const uint4*)(Bp + k1);     b_r[1] = *(const uint4*)(Bp + k1 + 8);
        }
#pragma unroll
        for (int c = 0; c < 2; ++c) {
            short8 af[2], bf[2];
#pragma unroll
            for (int i = 0; i < 2; ++i)
                af[i] = *(const short8*)&As[cur][wm + i * 16 + l15][c * 32 + quad * 8];
#pragma unroll
            for (int j = 0; j < 2; ++j)
                bf[j] = *(const short8*)&Bs[cur][wn + j * 16 + l15][c * 32 + quad * 8];
#pragma unroll
            for (int i = 0; i < 2; ++i)
#pragma unroll
                for (int j = 0; j < 2; ++j)
                    acc[i][j] = __builtin_amdgcn_mfma_f32_16x16x32_bf16(af[i], bf[j], acc[i][j], 0, 0, 0);
        }
        if (more) {
            const int nx = cur ^ 1;
            *(uint4*)&As[nx][srow][sk]     = a_r[0];
            *(uint4*)&As[nx][srow][sk + 8] = a_r[1];
            *(uint4*)&Bs[nx][srow][sk]     = b_r[0];
            *(uint4*)&Bs[nx][srow][sk + 8] = b_r[1];
            __syncthreads();
        }
    }

#pragma unroll
    for (int i = 0; i < 2; ++i)
#pragma unroll
        for (int j = 0; j < 2; ++j) {
            const int cl = nl0 + wn + j * 16 + l15;
#pragma unroll
            for (int r4 = 0; r4 < 4; ++r4) {
                const int r = m0 + wm + i * 16 + quad * 4 + r4;
                Dout[(size_t)r * 1024 + cl] = acc[i][j][r4];
            }
        }
}

// ---------------------------------------------------------------------------
// MFMA flash attention, 32x32x16, IN-BLOCK key-split (no combine pass).
// Grid (32 qtiles, 16 heads) = 512 blocks, 256 thr / 4 waves, 2 blocks/CU.
// Block = 64 queries. Wave w: qgrp = w&1 (q 0..31 / 32..63),
// khalf = w>>1 (keys 0..1023 / 1024..2047). 16 rounds of 64 keys per half.
// l via ones-column MFMA (row-sum on the matrix pipe, O's C-layout).
// Partials merged through LDS (Ks reused), bf16 out.
// ---------------------------------------------------------------------------
__global__ __launch_bounds__(256, 2) void attn(
    const u16* __restrict__ Qb, const u16* __restrict__ Kb,
    const u16* __restrict__ FV, u16* __restrict__ Ob)
{
    __shared__ u16 Ks[2][2][64][72];  // [buf][khalf][key][d], row 144B conflict-free
    __shared__ u16 Ps[4][32][40];     // [wave][q][key(32)+pad]

    const int t = threadIdx.x;
    const int n0 = blockIdx.x * 64;
    const int h = blockIdx.y, kvh = h >> 2;
    const int w = t >> 6, lane = t & 63;
    const int hi = lane >> 5, l31 = lane & 31;
    const int qgrp = w & 1, khalf = w >> 1;
    const int srow = t >> 1, ssel = (t & 1) * 32;   // staging: 2x64 rows x 64d
    const int khalf_s = srow >> 6, klocal = srow & 63;

    const short8 ones = {(short)0x3F80, (short)0x3F80, (short)0x3F80, (short)0x3F80,
                         (short)0x3F80, (short)0x3F80, (short)0x3F80, (short)0x3F80};

    // Q B-frags: B[k=d][n=q], q = n0 + qgrp*32 + l31, d = s*16 + hi*8 + j
    const u16* qp = Qb + (size_t)(n0 + qgrp * 32 + l31) * (NH * HDIM) + h * HDIM + hi * 8;
    short8 qf[4];
#pragma unroll
    for (int s = 0; s < 4; ++s) qf[s] = *(const short8*)(qp + s * 16);

    const u16* kbase = Kb + (size_t)(khalf_s * 1024 + klocal) * (NKV * HDIM) + kvh * HDIM + ssel;
    const u16* fvb = FV + ((size_t)kvh * 16 * 8192) + (size_t)lane * 8;

    f32x16 o[2], o_l;
#pragma unroll
    for (int d2 = 0; d2 < 2; ++d2)
#pragma unroll
        for (int r = 0; r < 16; ++r) o[d2][r] = 0.f;
#pragma unroll
    for (int r = 0; r < 16; ++r) o_l[r] = 0.f;

    // prologue: first 64 keys of each half -> buf 0
#pragma unroll
    for (int c = 0; c < 4; ++c)
        *(uint4*)&Ks[0][khalf_s][klocal][ssel + c * 8] = *(const uint4*)(kbase + c * 8);
    __syncthreads();

    for (int rd = 0; rd < 16; ++rd) {
        const int cur = rd & 1, nxt = cur ^ 1;
        const int rdn = (rd + 1) & 15;            // wrap: dead store on last round
        uint4 kr[4];
#pragma unroll
        for (int c = 0; c < 4; ++c)
            kr[c] = *(const uint4*)(kbase + (size_t)(rdn * 64) * (NKV * HDIM) + c * 8);

#pragma unroll
        for (int kg = 0; kg < 2; ++kg) {
            const int kg_global = khalf * 32 + rd * 2 + kg;   // 32-key group 0..63
            const int keyblk = kg_global >> 2, kgi = kg_global & 3;
            // ---- V frags (global, coalesced; used after softmax) ----
            short8 vf[2][2];
#pragma unroll
            for (int s = 0; s < 2; ++s)
#pragma unroll
                for (int d2 = 0; d2 < 2; ++d2)
                    vf[s][d2] = *(const short8*)(fvb +
                        ((((size_t)keyblk * 4 + kgi) * 2 + s) * 2 + d2) * 512);
            // ---- S^T = K Q^T over d=64 (4 ksteps of 16) ----
            f32x16 sa;
#pragma unroll
            for (int r = 0; r < 16; ++r) sa[r] = 0.f;
#pragma unroll
            for (int s = 0; s < 4; ++s) {
                short8 kf = *(const short8*)&Ks[cur][khalf][kg * 32 + l31][s * 16 + hi * 8];
                sa = __builtin_amdgcn_mfma_f32_32x32x16_bf16(kf, qf[s], sa, 0, 0, 0);
            }
            // ---- p = exp2(s); P -> Ps (key rows (r&3)+8*(r>>2)+4*hi) ----
            float p[16];
#pragma unroll
            for (int r = 0; r < 16; ++r) p[r] = __builtin_amdgcn_exp2f(sa[r]);
#pragma unroll
            for (int blk = 0; blk < 4; ++blk) {
                uint2 pk;
                pk.x = pack2t(p[blk * 4 + 0], p[blk * 4 + 1]);
                pk.y = pack2t(p[blk * 4 + 2], p[blk * 4 + 3]);
                *(uint2*)&Ps[w][l31][blk * 8 + 4 * hi] = pk;
            }
            const short8 ap0 = *(const short8*)&Ps[w][l31][hi * 8];
            const short8 ap1 = *(const short8*)&Ps[w][l31][16 + hi * 8];
            // ---- O += P V ; l += P 1 (row-sum on the matrix pipe) ----
#pragma unroll
            for (int d2 = 0; d2 < 2; ++d2) {
                o[d2] = __builtin_amdgcn_mfma_f32_32x32x16_bf16(ap0, vf[0][d2], o[d2], 0, 0, 0);
                o[d2] = __builtin_amdgcn_mfma_f32_32x32x16_bf16(ap1, vf[1][d2], o[d2], 0, 0, 0);
            }
            o_l = __builtin_amdgcn_mfma_f32_32x32x16_bf16(ap0, ones, o_l, 0, 0, 0);
            o_l = __builtin_amdgcn_mfma_f32_32x32x16_bf16(ap1, ones, o_l, 0, 0, 0);
        }
        // ---- stage next 64-key tiles (both halves); single barrier ----
#pragma unroll
        for (int c = 0; c < 4; ++c)
            *(uint4*)&Ks[nxt][khalf_s][klocal][ssel + c * 8] = kr[c];
        __syncthreads();
    }

    // ---- merge key halves through LDS (reuse Ks) and write bf16 ----
    float* Xf = (float*)&Ks[0][0][0][0];   // Ox[2][32][64] (4096 f32) + Lx[64]
    if (khalf == 1) {
#pragma unroll
        for (int d2 = 0; d2 < 2; ++d2)
#pragma unroll
            for (int r = 0; r < 16; ++r) {
                const int q32 = (r & 3) + 8 * (r >> 2) + 4 * hi;
                Xf[qgrp * 2048 + q32 * 64 + d2 * 32 + l31] = o[d2][r];
            }
        if (l31 == 0) {
#pragma unroll
            for (int r = 0; r < 16; ++r) {
                const int q32 = (r & 3) + 8 * (r >> 2) + 4 * hi;
                Xf[4096 + qgrp * 32 + q32] = o_l[r];
            }
        }
    }
    __syncthreads();
    if (khalf == 0) {
        float linv[16];
#pragma unroll
        for (int r = 0; r < 16; ++r) {
            const int q32 = (r & 3) + 8 * (r >> 2) + 4 * hi;
            linv[r] = 1.f / (o_l[r] + Xf[4096 + qgrp * 32 + q32]);
        }
#pragma unroll
        for (int d2 = 0; d2 < 2; ++d2)
#pragma unroll
            for (int r = 0; r < 16; ++r) {
                const int q32 = (r & 3) + 8 * (r >> 2) + 4 * hi;
                const float val = o[d2][r] + Xf[qgrp * 2048 + q32 * 64 + d2 * 32 + l31];
                const int qrow = n0 + qgrp * 32 + q32;
                Ob[(size_t)qrow * (NH * HDIM) + h * HDIM + d2 * 32 + l31] = f2bf(val * linv[r]);
            }
    }
}

// ---------------------------------------------------------------------------
extern "C" void kernel_launch(void* const* d_in, const int* in_sizes, int n_in,
                              void* d_out, int out_size, void* d_ws, size_t ws_size,
                              hipStream_t stream) {
    const float* x  = (const float*)d_in[0];
    const float* fc = (const float*)d_in[1];
    const float* fs = (const float*)d_in[2];
    const float* Wq = (const float*)d_in[3];
    const float* Wk = (const float*)d_in[4];
    const float* Wv = (const float*)d_in[5];
    const float* Wo = (const float*)d_in[6];
    float* out = (float*)d_out;

    u16* ws  = (u16*)d_ws;
    u16* Wqt = ws;                         // 1024*1024
    u16* Wkt = Wqt + (size_t)1024 * 1024;  // 256*1024
    u16* Wvt = Wkt + (size_t)256 * 1024;   // 256*1024
    u16* Wot = Wvt + (size_t)256 * 1024;   // 1024*1024
    u16* qb  = Wot + (size_t)1024 * 1024;  // 2048*1024
    u16* kb  = qb  + (size_t)2048 * 1024;  // 2048*256
    u16* fv  = kb  + (size_t)2048 * 256;   // 256*2048 (fragment-packed V, 32-wide)
    u16* aob = fv  + (size_t)256 * 2048;   // 2048*1024

    prep<<<dim3(16, 16, 4), dim3(256), 0, stream>>>(Wq, Wk, Wv, Wo,
                                                    Wqt, Wkt, Wvt, Wot);
    gemm_qkv<<<dim3(16, 24), dim3(256), 0, stream>>>(x, Wqt, Wkt, Wvt,
                                                     qb, kb, fv, fc, fs);
    attn<<<dim3(32, 16), dim3(256), 0, stream>>>(qb, kb, fv, aob);
    gemm_out<<<dim3(32, 16), dim3(256), 0, stream>>>(aob, Wot, out);
}

// Round 7
// 138.530 us; speedup vs baseline: 2.5315x; 1.1733x over previous
//
#include <hip/hip_runtime.h>

#define N_TOK 2048
#define DMODEL 1024
#define NH 16
#define NKV 4
#define HDIM 64
#define SCALE_LOG2E 0.1803368801111204f  // (1/8) * log2(e)

typedef __attribute__((ext_vector_type(8))) short short8;
typedef __attribute__((ext_vector_type(4))) float f32x4;
typedef __attribute__((ext_vector_type(16))) float f32x16;
typedef unsigned short u16;
typedef unsigned int u32;

__device__ __forceinline__ u16 f2bf(float x) {
    u32 u = __float_as_uint(x);
    u += 0x7FFF + ((u >> 16) & 1);   // round-to-nearest-even
    return (u16)(u >> 16);
}
__device__ __forceinline__ u32 pack2(float a, float b) {
    return (u32)f2bf(a) | ((u32)f2bf(b) << 16);
}
// pack high halves (truncating bf16) of two floats: [bf(a) | bf(b)<<16]
__device__ __forceinline__ u32 pack2t(float a, float b) {
    return __builtin_amdgcn_perm(__float_as_uint(b), __float_as_uint(a), 0x07060302u);
}

// async global->LDS, 16B/lane: HW writes lds_base + lane*16 (wave-uniform base).
__device__ __forceinline__ void gload16(const u16* g, u16* l) {
    __builtin_amdgcn_global_load_lds(
        (const __attribute__((address_space(1))) unsigned int*)g,
        (__attribute__((address_space(3))) unsigned int*)l, 16, 0, 0);
}

// ---------------------------------------------------------------------------
// prep: z=0..3 transpose W (K x NC) -> Wt (NC x K) bf16; z=4 convert x -> bf16
// ---------------------------------------------------------------------------
__global__ __launch_bounds__(256) void prep(
    const float* __restrict__ Wq, const float* __restrict__ Wk,
    const float* __restrict__ Wv, const float* __restrict__ Wo,
    const float* __restrict__ x,
    u16* __restrict__ Wqt, u16* __restrict__ Wkt, u16* __restrict__ Wvt,
    u16* __restrict__ Wot, u16* __restrict__ xb)
{
    const int z = blockIdx.z;
    const int t = threadIdx.x;
    if (z == 4) {
        size_t base = ((size_t)(blockIdx.y * 16 + blockIdx.x)) * 8192;
#pragma unroll
        for (int i = 0; i < 8; ++i) {
            float4 v = *(const float4*)(x + base + i * 1024 + t * 4);
            uint2 p; p.x = pack2(v.x, v.y); p.y = pack2(v.z, v.w);
            *(uint2*)(xb + base + i * 1024 + t * 4) = p;
        }
        return;
    }
    const float* W; u16* Wt; int NC;
    if      (z == 0) { W = Wq; Wt = Wqt; NC = 1024; }
    else if (z == 1) { W = Wk; Wt = Wkt; NC = 256; }
    else if (z == 2) { W = Wv; Wt = Wvt; NC = 256; }
    else             { W = Wo; Wt = Wot; NC = 1024; }
    const int n0 = blockIdx.x * 64;
    if (n0 >= NC) return;
    const int k0 = blockIdx.y * 64;
    __shared__ float T[64][68];
    const int row = t >> 2, cs = (t & 3) * 16;
#pragma unroll
    for (int i = 0; i < 4; ++i)
        *(float4*)&T[row][cs + i * 4] =
            *(const float4*)(W + (size_t)(k0 + row) * NC + n0 + cs + i * 4);
    __syncthreads();
    const int nl = t >> 2, ks = (t & 3) * 16;
    u32 pk[8];
#pragma unroll
    for (int i = 0; i < 8; ++i)
        pk[i] = pack2(T[ks + 2 * i][nl], T[ks + 2 * i + 1][nl]);
    u16* dst = Wt + (size_t)(n0 + nl) * DMODEL + k0 + ks;
    uint4 w0; w0.x = pk[0]; w0.y = pk[1]; w0.z = pk[2]; w0.w = pk[3];
    uint4 w1; w1.x = pk[4]; w1.y = pk[5]; w1.z = pk[6]; w1.w = pk[7];
    *(uint4*)(dst) = w0;
    *(uint4*)(dst + 8) = w1;
}

// ---------------------------------------------------------------------------
// QKV GEMM: tile 64x64, BK=64, global_load_lds staging into LINEAR dbuf LDS
// with both-sides XOR swizzle (chunk p of row r holds global chunk p^(r&7);
// r&7 == lane>>3 at stage time, so per-lane source col = ((lane&7)^(lane>>3))*8).
// ONE barrier per K-iter; staging issue overlaps MFMA. 4 waves of 32x32.
// grid (32,24) = 768 blocks -> 3 blocks/CU.
// by<16 -> Q (rope, x SCALE_LOG2E); 16..19 -> K (rope); 20..23 -> V in FV2:
//   FV2[((((((g*16+keyblk)*4+kg)*2+kstep)*2+dgrp)*2+hi)*32+dl)*8+j]
//     = V[key = keyblk*128 + kg*32 + kstep*16 + hi*8 + j][d = dgrp*32 + dl]
// ---------------------------------------------------------------------------
__global__ __launch_bounds__(256, 3) void gemm_qkv(
    const u16* __restrict__ A,
    const u16* __restrict__ B0, const u16* __restrict__ B1, const u16* __restrict__ B2,
    u16* __restrict__ D0, u16* __restrict__ D1, u16* __restrict__ FVout,
    const float* __restrict__ fc, const float* __restrict__ fs)
{
    __shared__ u16 As[2][64][64];   // linear: required by global_load_lds
    __shared__ u16 Bs[2][64][64];
    const int t = threadIdx.x;
    const int m0 = blockIdx.x * 64;
    const int by = blockIdx.y;

    const u16* Bt; int nl0, ep;           // ep: 1 rope bf16, 2 FV2
    u16* dbf = nullptr; int dstride = 0; float epsc = 1.f;
    if (by < 16)      { Bt = B0; nl0 = by * 64;        dbf = D0; ep = 1; dstride = 1024;
                        epsc = SCALE_LOG2E; }
    else if (by < 20) { Bt = B1; nl0 = (by - 16) * 64; dbf = D1; ep = 1; dstride = 256; }
    else              { Bt = B2; nl0 = (by - 20) * 64; ep = 2; }

    const int w = t >> 6, lane = t & 63;
    const int quad = lane >> 4, l15 = lane & 15;
    const int wm = (w >> 1) * 32, wn = (w & 1) * 32;
    const int rx = l15 & 7;                         // read-side swizzle key

    // staging: wave w covers tile rows [w*16, w*16+16), 2 instrs x 8 rows each
    const int sro = w * 16 + (lane >> 3);           // per-lane staged row
    const int sco = ((lane & 7) ^ (lane >> 3)) * 8; // pre-swizzled source col
    const u16* ApL = A + (size_t)(m0 + sro) * DMODEL + sco;
    const u16* BpL = Bt + (size_t)(nl0 + sro) * DMODEL + sco;

    f32x4 acc[2][2];
#pragma unroll
    for (int i = 0; i < 2; ++i)
#pragma unroll
        for (int j = 0; j < 2; ++j) acc[i][j] = {0.f, 0.f, 0.f, 0.f};

    // prologue: stage tile 0 -> buf 0
#pragma unroll
    for (int k = 0; k < 2; ++k) {
        gload16(ApL + k * 8 * DMODEL, &As[0][w * 16 + k * 8][0]);
        gload16(BpL + k * 8 * DMODEL, &Bs[0][w * 16 + k * 8][0]);
    }
    __syncthreads();

    for (int it = 0; it < 16; ++it) {
        const int cur = it & 1;
        if (it + 1 < 16) {
            const int kk = (it + 1) * 64;
#pragma unroll
            for (int k = 0; k < 2; ++k) {
                gload16(ApL + k * 8 * DMODEL + kk, &As[cur ^ 1][w * 16 + k * 8][0]);
                gload16(BpL + k * 8 * DMODEL + kk, &Bs[cur ^ 1][w * 16 + k * 8][0]);
            }
        }
#pragma unroll
        for (int c = 0; c < 2; ++c) {
            short8 af[2], bf[2];
#pragma unroll
            for (int i = 0; i < 2; ++i)
                af[i] = *(const short8*)&As[cur][wm + i * 16 + l15][((4 * c + quad) ^ rx) * 8];
#pragma unroll
            for (int j = 0; j < 2; ++j)
                bf[j] = *(const short8*)&Bs[cur][wn + j * 16 + l15][((4 * c + quad) ^ rx) * 8];
#pragma unroll
            for (int i = 0; i < 2; ++i)
#pragma unroll
                for (int j = 0; j < 2; ++j)
                    acc[i][j] = __builtin_amdgcn_mfma_f32_16x16x32_bf16(af[i], bf[j], acc[i][j], 0, 0, 0);
        }
        __syncthreads();   // drains gload (next buf ready) + all reads of cur done
    }

#pragma unroll
    for (int i = 0; i < 2; ++i)
#pragma unroll
        for (int j = 0; j < 2; ++j) {
            const int cl = nl0 + wn + j * 16 + l15;
            if (ep == 1) {
#pragma unroll
                for (int r4 = 0; r4 < 4; ++r4) {
                    const int r = m0 + wm + i * 16 + quad * 4 + r4;
                    float own = acc[i][j][r4];
                    float other = __shfl_xor(own, 1, 64);
                    const int p = (cl & 63) >> 1;
                    const float c = fc[r * 32 + p] * epsc, s = fs[r * 32 + p] * epsc;
                    float outv = ((cl & 1) == 0) ? (own * c - other * s)
                                                 : (other * s + own * c);
                    dbf[(size_t)r * dstride + cl] = f2bf(outv);
                }
            } else {
                // packed 4-key store: r4=0..3 are consecutive jv in FV2
                const int rb = m0 + wm + i * 16 + quad * 4;
                const int g = cl >> 6, d = cl & 63;
                const int d2 = d >> 5, dl = d & 31;
                const int keyblk = rb >> 7, kg = (rb >> 5) & 3;
                const int kst = (rb >> 4) & 1, hb = (rb >> 3) & 1, jv = rb & 7;
                size_t idx = ((((((size_t)(g * 16 + keyblk) * 4 + kg) * 2 + kst) * 2 + d2)
                               * 2 + hb) * 32 + dl) * 8 + jv;
                uint2 pk;
                pk.x = pack2(acc[i][j][0], acc[i][j][1]);
                pk.y = pack2(acc[i][j][2], acc[i][j][3]);
                *(uint2*)(FVout + idx) = pk;
            }
        }
}

// ---------------------------------------------------------------------------
// Output GEMM: same gload_lds + swizzle structure, tile 64x64, fp32 out.
// grid (32,16) = 512 blocks -> 2 blocks/CU even.
// ---------------------------------------------------------------------------
__global__ __launch_bounds__(256, 2) void gemm_out(
    const u16* __restrict__ A, const u16* __restrict__ Bt, float* __restrict__ Dout)
{
    __shared__ u16 As[2][64][64];
    __shared__ u16 Bs[2][64][64];
    const int t = threadIdx.x;
    const int m0 = blockIdx.x * 64;
    const int nl0 = blockIdx.y * 64;

    const int w = t >> 6, lane = t & 63;
    const int quad = lane >> 4, l15 = lane & 15;
    const int wm = (w >> 1) * 32, wn = (w & 1) * 32;
    const int rx = l15 & 7;

    const int sro = w * 16 + (lane >> 3);
    const int sco = ((lane & 7) ^ (lane >> 3)) * 8;
    const u16* ApL = A + (size_t)(m0 + sro) * DMODEL + sco;
    const u16* BpL = Bt + (size_t)(nl0 + sro) * DMODEL + sco;

    f32x4 acc[2][2];
#pragma unroll
    for (int i = 0; i < 2; ++i)
#pragma unroll
        for (int j = 0; j < 2; ++j) acc[i][j] = {0.f, 0.f, 0.f, 0.f};

#pragma unroll
    for (int k = 0; k < 2; ++k) {
        gload16(ApL + k * 8 * DMODEL, &As[0][w * 16 + k * 8][0]);
        gload16(BpL + k * 8 * DMODEL, &Bs[0][w * 16 + k * 8][0]);
    }
    __syncthreads();

    for (int it = 0; it < 16; ++it) {
        const int cur = it & 1;
        if (it + 1 < 16) {
            const int kk = (it + 1) * 64;
#pragma unroll
            for (int k = 0; k < 2; ++k) {
                gload16(ApL + k * 8 * DMODEL + kk, &As[cur ^ 1][w * 16 + k * 8][0]);
                gload16(BpL + k * 8 * DMODEL + kk, &Bs[cur ^ 1][w * 16 + k * 8][0]);
            }
        }
#pragma unroll
        for (int c = 0; c < 2; ++c) {
            short8 af[2], bf[2];
#pragma unroll
            for (int i = 0; i < 2; ++i)
                af[i] = *(const short8*)&As[cur][wm + i * 16 + l15][((4 * c + quad) ^ rx) * 8];
#pragma unroll
            for (int j = 0; j < 2; ++j)
                bf[j] = *(const short8*)&Bs[cur][wn + j * 16 + l15][((4 * c + quad) ^ rx) * 8];
#pragma unroll
            for (int i = 0; i < 2; ++i)
#pragma unroll
                for (int j = 0; j < 2; ++j)
                    acc[i][j] = __builtin_amdgcn_mfma_f32_16x16x32_bf16(af[i], bf[j], acc[i][j], 0, 0, 0);
        }
        __syncthreads();
    }

#pragma unroll
    for (int i = 0; i < 2; ++i)
#pragma unroll
        for (int j = 0; j < 2; ++j) {
            const int cl = nl0 + wn + j * 16 + l15;
#pragma unroll
            for (int r4 = 0; r4 < 4; ++r4) {
                const int r = m0 + wm + i * 16 + quad * 4 + r4;
                Dout[(size_t)r * 1024 + cl] = acc[i][j][r4];
            }
        }
}

// ---------------------------------------------------------------------------
// MFMA flash attention, 32x32x16, IN-BLOCK key-split (no combine pass).
// Grid (32 qtiles, 16 heads) = 512 blocks, 256 thr / 4 waves, 2 blocks/CU.
// Block = 64 queries. Wave w: qgrp = w&1 (q 0..31 / 32..63),
// khalf = w>>1 (keys 0..1023 / 1024..2047). 16 rounds of 64 keys per half.
// l via ones-column MFMA (row-sum on the matrix pipe, O's C-layout).
// Partials merged through LDS (Ks reused), bf16 out.
// ---------------------------------------------------------------------------
__global__ __launch_bounds__(256, 2) void attn(
    const u16* __restrict__ Qb, const u16* __restrict__ Kb,
    const u16* __restrict__ FV, u16* __restrict__ Ob)
{
    __shared__ u16 Ks[2][2][64][72];  // [buf][khalf][key][d], row 144B conflict-free
    __shared__ u16 Ps[4][32][40];     // [wave][q][key(32)+pad]

    const int t = threadIdx.x;
    const int n0 = blockIdx.x * 64;
    const int h = blockIdx.y, kvh = h >> 2;
    const int w = t >> 6, lane = t & 63;
    const int hi = lane >> 5, l31 = lane & 31;
    const int qgrp = w & 1, khalf = w >> 1;
    const int srow = t >> 1, ssel = (t & 1) * 32;   // staging: 2x64 rows x 64d
    const int khalf_s = srow >> 6, klocal = srow & 63;

    const short8 ones = {(short)0x3F80, (short)0x3F80, (short)0x3F80, (short)0x3F80,
                         (short)0x3F80, (short)0x3F80, (short)0x3F80, (short)0x3F80};

    // Q B-frags: B[k=d][n=q], q = n0 + qgrp*32 + l31, d = s*16 + hi*8 + j
    const u16* qp = Qb + (size_t)(n0 + qgrp * 32 + l31) * (NH * HDIM) + h * HDIM + hi * 8;
    short8 qf[4];
#pragma unroll
    for (int s = 0; s < 4; ++s) qf[s] = *(const short8*)(qp + s * 16);

    const u16* kbase = Kb + (size_t)(khalf_s * 1024 + klocal) * (NKV * HDIM) + kvh * HDIM + ssel;
    const u16* fvb = FV + ((size_t)kvh * 16 * 8192) + (size_t)lane * 8;

    f32x16 o[2], o_l;
#pragma unroll
    for (int d2 = 0; d2 < 2; ++d2)
#pragma unroll
        for (int r = 0; r < 16; ++r) o[d2][r] = 0.f;
#pragma unroll
    for (int r = 0; r < 16; ++r) o_l[r] = 0.f;

    // prologue: first 64 keys of each half -> buf 0
#pragma unroll
    for (int c = 0; c < 4; ++c)
        *(uint4*)&Ks[0][khalf_s][klocal][ssel + c * 8] = *(const uint4*)(kbase + c * 8);
    __syncthreads();

    for (int rd = 0; rd < 16; ++rd) {
        const int cur = rd & 1, nxt = cur ^ 1;
        const int rdn = (rd + 1) & 15;            // wrap: dead store on last round
        uint4 kr[4];
#pragma unroll
        for (int c = 0; c < 4; ++c)
            kr[c] = *(const uint4*)(kbase + (size_t)(rdn * 64) * (NKV * HDIM) + c * 8);

#pragma unroll
        for (int kg = 0; kg < 2; ++kg) {
            const int kg_global = khalf * 32 + rd * 2 + kg;   // 32-key group 0..63
            const int keyblk = kg_global >> 2, kgi = kg_global & 3;
            // ---- V frags (global, coalesced; used after softmax) ----
            short8 vf[2][2];
#pragma unroll
            for (int s = 0; s < 2; ++s)
#pragma unroll
                for (int d2 = 0; d2 < 2; ++d2)
                    vf[s][d2] = *(const short8*)(fvb +
                        ((((size_t)keyblk * 4 + kgi) * 2 + s) * 2 + d2) * 512);
            // ---- S^T = K Q^T over d=64 (4 ksteps of 16) ----
            f32x16 sa;
#pragma unroll
            for (int r = 0; r < 16; ++r) sa[r] = 0.f;
#pragma unroll
            for (int s = 0; s < 4; ++s) {
                short8 kf = *(const short8*)&Ks[cur][khalf][kg * 32 + l31][s * 16 + hi * 8];
                sa = __builtin_amdgcn_mfma_f32_32x32x16_bf16(kf, qf[s], sa, 0, 0, 0);
            }
            // ---- p = exp2(s); P -> Ps (key rows (r&3)+8*(r>>2)+4*hi) ----
            float p[16];
#pragma unroll
            for (int r = 0; r < 16; ++r) p[r] = __builtin_amdgcn_exp2f(sa[r]);
#pragma unroll
            for (int blk = 0; blk < 4; ++blk) {
                uint2 pk;
                pk.x = pack2t(p[blk * 4 + 0], p[blk * 4 + 1]);
                pk.y = pack2t(p[blk * 4 + 2], p[blk * 4 + 3]);
                *(uint2*)&Ps[w][l31][blk * 8 + 4 * hi] = pk;
            }
            const short8 ap0 = *(const short8*)&Ps[w][l31][hi * 8];
            const short8 ap1 = *(const short8*)&Ps[w][l31][16 + hi * 8];
            // ---- O += P V ; l += P 1 (row-sum on the matrix pipe) ----
#pragma unroll
            for (int d2 = 0; d2 < 2; ++d2) {
                o[d2] = __builtin_amdgcn_mfma_f32_32x32x16_bf16(ap0, vf[0][d2], o[d2], 0, 0, 0);
                o[d2] = __builtin_amdgcn_mfma_f32_32x32x16_bf16(ap1, vf[1][d2], o[d2], 0, 0, 0);
            }
            o_l = __builtin_amdgcn_mfma_f32_32x32x16_bf16(ap0, ones, o_l, 0, 0, 0);
            o_l = __builtin_amdgcn_mfma_f32_32x32x16_bf16(ap1, ones, o_l, 0, 0, 0);
        }
        // ---- stage next 64-key tiles (both halves); single barrier ----
#pragma unroll
        for (int c = 0; c < 4; ++c)
            *(uint4*)&Ks[nxt][khalf_s][klocal][ssel + c * 8] = kr[c];
        __syncthreads();
    }

    // ---- merge key halves through LDS (reuse Ks) and write bf16 ----
    float* Xf = (float*)&Ks[0][0][0][0];   // Ox[2][32][64] (4096 f32) + Lx[64]
    if (khalf == 1) {
#pragma unroll
        for (int d2 = 0; d2 < 2; ++d2)
#pragma unroll
            for (int r = 0; r < 16; ++r) {
                const int q32 = (r & 3) + 8 * (r >> 2) + 4 * hi;
                Xf[qgrp * 2048 + q32 * 64 + d2 * 32 + l31] = o[d2][r];
            }
        if (l31 == 0) {
#pragma unroll
            for (int r = 0; r < 16; ++r) {
                const int q32 = (r & 3) + 8 * (r >> 2) + 4 * hi;
                Xf[4096 + qgrp * 32 + q32] = o_l[r];
            }
        }
    }
    __syncthreads();
    if (khalf == 0) {
        float linv[16];
#pragma unroll
        for (int r = 0; r < 16; ++r) {
            const int q32 = (r & 3) + 8 * (r >> 2) + 4 * hi;
            linv[r] = 1.f / (o_l[r] + Xf[4096 + qgrp * 32 + q32]);
        }
#pragma unroll
        for (int d2 = 0; d2 < 2; ++d2)
#pragma unroll
            for (int r = 0; r < 16; ++r) {
                const int q32 = (r & 3) + 8 * (r >> 2) + 4 * hi;
                const float val = o[d2][r] + Xf[qgrp * 2048 + q32 * 64 + d2 * 32 + l31];
                const int qrow = n0 + qgrp * 32 + q32;
                Ob[(size_t)qrow * (NH * HDIM) + h * HDIM + d2 * 32 + l31] = f2bf(val * linv[r]);
            }
    }
}

// ---------------------------------------------------------------------------
extern "C" void kernel_launch(void* const* d_in, const int* in_sizes, int n_in,
                              void* d_out, int out_size, void* d_ws, size_t ws_size,
                              hipStream_t stream) {
    const float* x  = (const float*)d_in[0];
    const float* fc = (const float*)d_in[1];
    const float* fs = (const float*)d_in[2];
    const float* Wq = (const float*)d_in[3];
    const float* Wk = (const float*)d_in[4];
    const float* Wv = (const float*)d_in[5];
    const float* Wo = (const float*)d_in[6];
    float* out = (float*)d_out;

    u16* ws  = (u16*)d_ws;
    u16* xb  = ws;                         // 2048*1024
    u16* Wqt = xb  + (size_t)2048 * 1024;  // 1024*1024
    u16* Wkt = Wqt + (size_t)1024 * 1024;  // 256*1024
    u16* Wvt = Wkt + (size_t)256 * 1024;   // 256*1024
    u16* Wot = Wvt + (size_t)256 * 1024;   // 1024*1024
    u16* qb  = Wot + (size_t)1024 * 1024;  // 2048*1024
    u16* kb  = qb  + (size_t)2048 * 1024;  // 2048*256
    u16* fv  = kb  + (size_t)2048 * 256;   // 256*2048 (fragment-packed V, 32-wide)
    u16* aob = fv  + (size_t)256 * 2048;   // 2048*1024

    prep<<<dim3(16, 16, 5), dim3(256), 0, stream>>>(Wq, Wk, Wv, Wo, x,
                                                    Wqt, Wkt, Wvt, Wot, xb);
    gemm_qkv<<<dim3(32, 24), dim3(256), 0, stream>>>(xb, Wqt, Wkt, Wvt,
                                                     qb, kb, fv, fc, fs);
    attn<<<dim3(32, 16), dim3(256), 0, stream>>>(qb, kb, fv, aob);
    gemm_out<<<dim3(32, 16), dim3(256), 0, stream>>>(aob, Wot, out);
}

// Round 8
// 136.138 us; speedup vs baseline: 2.5759x; 1.0176x over previous
//
#include <hip/hip_runtime.h>

#define N_TOK 2048
#define DMODEL 1024
#define NH 16
#define NKV 4
#define HDIM 64
#define SCALE_LOG2E 0.1803368801111204f  // (1/8) * log2(e)

typedef __attribute__((ext_vector_type(8))) short short8;
typedef __attribute__((ext_vector_type(4))) float f32x4;
typedef __attribute__((ext_vector_type(16))) float f32x16;
typedef __attribute__((ext_vector_type(2))) int i32x2;
typedef __attribute__((ext_vector_type(4))) unsigned int u32x4;
typedef unsigned short u16;
typedef unsigned int u32;

__device__ __forceinline__ u16 f2bf(float x) {
    u32 u = __float_as_uint(x);
    u += 0x7FFF + ((u >> 16) & 1);   // round-to-nearest-even
    return (u16)(u >> 16);
}
__device__ __forceinline__ u32 pack2(float a, float b) {
    return (u32)f2bf(a) | ((u32)f2bf(b) << 16);
}
// pack high halves (truncating bf16) of two floats: [bf(a) | bf(b)<<16]
__device__ __forceinline__ u32 pack2t(float a, float b) {
    return __builtin_amdgcn_perm(__float_as_uint(b), __float_as_uint(a), 0x07060302u);
}

// async global->LDS, 16B/lane: HW writes lds_base + lane*16 (wave-uniform base).
__device__ __forceinline__ void gload16(const u16* g, u16* l) {
    __builtin_amdgcn_global_load_lds(
        (const __attribute__((address_space(1))) unsigned int*)g,
        (__attribute__((address_space(3))) unsigned int*)l, 16, 0, 0);
}

// ---------------------------------------------------------------------------
// prep: z=0..3 transpose W (K x NC) -> Wt (NC x K) bf16; z=4 convert x -> bf16
// ---------------------------------------------------------------------------
__global__ __launch_bounds__(256) void prep(
    const float* __restrict__ Wq, const float* __restrict__ Wk,
    const float* __restrict__ Wv, const float* __restrict__ Wo,
    const float* __restrict__ x,
    u16* __restrict__ Wqt, u16* __restrict__ Wkt, u16* __restrict__ Wvt,
    u16* __restrict__ Wot, u16* __restrict__ xb)
{
    const int z = blockIdx.z;
    const int t = threadIdx.x;
    if (z == 4) {
        size_t base = ((size_t)(blockIdx.y * 16 + blockIdx.x)) * 8192;
#pragma unroll
        for (int i = 0; i < 8; ++i) {
            float4 v = *(const float4*)(x + base + i * 1024 + t * 4);
            uint2 p; p.x = pack2(v.x, v.y); p.y = pack2(v.z, v.w);
            *(uint2*)(xb + base + i * 1024 + t * 4) = p;
        }
        return;
    }
    const float* W; u16* Wt; int NC;
    if      (z == 0) { W = Wq; Wt = Wqt; NC = 1024; }
    else if (z == 1) { W = Wk; Wt = Wkt; NC = 256; }
    else if (z == 2) { W = Wv; Wt = Wvt; NC = 256; }
    else             { W = Wo; Wt = Wot; NC = 1024; }
    const int n0 = blockIdx.x * 64;
    if (n0 >= NC) return;
    const int k0 = blockIdx.y * 64;
    __shared__ float T[64][68];
    const int row = t >> 2, cs = (t & 3) * 16;
#pragma unroll
    for (int i = 0; i < 4; ++i)
        *(float4*)&T[row][cs + i * 4] =
            *(const float4*)(W + (size_t)(k0 + row) * NC + n0 + cs + i * 4);
    __syncthreads();
    const int nl = t >> 2, ks = (t & 3) * 16;
    u32 pk[8];
#pragma unroll
    for (int i = 0; i < 8; ++i)
        pk[i] = pack2(T[ks + 2 * i][nl], T[ks + 2 * i + 1][nl]);
    u16* dst = Wt + (size_t)(n0 + nl) * DMODEL + k0 + ks;
    uint4 w0; w0.x = pk[0]; w0.y = pk[1]; w0.z = pk[2]; w0.w = pk[3];
    uint4 w1; w1.x = pk[4]; w1.y = pk[5]; w1.z = pk[6]; w1.w = pk[7];
    *(uint4*)(dst) = w0;
    *(uint4*)(dst + 8) = w1;
}

// ---------------------------------------------------------------------------
// QKV GEMM: tile 64x64, BK=64, global_load_lds staging into LINEAR dbuf LDS
// with both-sides XOR swizzle. ONE barrier per K-iter. 4 waves of 32x32.
// grid (32,24) = 768 blocks -> 3 blocks/CU.
// by<16 -> Q (rope, x SCALE_LOG2E); 16..19 -> K (rope); 20..23 -> V in FV2:
//   FV2[((((((g*16+keyblk)*4+kg)*2+kstep)*2+dgrp)*2+hi)*32+dl)*8+j]
//     = V[key = keyblk*128 + kg*32 + kstep*16 + hi*8 + j][d = dgrp*32 + dl]
// ---------------------------------------------------------------------------
__global__ __launch_bounds__(256, 3) void gemm_qkv(
    const u16* __restrict__ A,
    const u16* __restrict__ B0, const u16* __restrict__ B1, const u16* __restrict__ B2,
    u16* __restrict__ D0, u16* __restrict__ D1, u16* __restrict__ FVout,
    const float* __restrict__ fc, const float* __restrict__ fs)
{
    __shared__ u16 As[2][64][64];   // linear: required by global_load_lds
    __shared__ u16 Bs[2][64][64];
    const int t = threadIdx.x;
    const int m0 = blockIdx.x * 64;
    const int by = blockIdx.y;

    const u16* Bt; int nl0, ep;           // ep: 1 rope bf16, 2 FV2
    u16* dbf = nullptr; int dstride = 0; float epsc = 1.f;
    if (by < 16)      { Bt = B0; nl0 = by * 64;        dbf = D0; ep = 1; dstride = 1024;
                        epsc = SCALE_LOG2E; }
    else if (by < 20) { Bt = B1; nl0 = (by - 16) * 64; dbf = D1; ep = 1; dstride = 256; }
    else              { Bt = B2; nl0 = (by - 20) * 64; ep = 2; }

    const int w = t >> 6, lane = t & 63;
    const int quad = lane >> 4, l15 = lane & 15;
    const int wm = (w >> 1) * 32, wn = (w & 1) * 32;
    const int rx = l15 & 7;                         // read-side swizzle key

    // staging: wave w covers tile rows [w*16, w*16+16), 2 instrs x 8 rows each
    const int sro = w * 16 + (lane >> 3);           // per-lane staged row
    const int sco = ((lane & 7) ^ (lane >> 3)) * 8; // pre-swizzled source col
    const u16* ApL = A + (size_t)(m0 + sro) * DMODEL + sco;
    const u16* BpL = Bt + (size_t)(nl0 + sro) * DMODEL + sco;

    f32x4 acc[2][2];
#pragma unroll
    for (int i = 0; i < 2; ++i)
#pragma unroll
        for (int j = 0; j < 2; ++j) acc[i][j] = {0.f, 0.f, 0.f, 0.f};

    // prologue: stage tile 0 -> buf 0
#pragma unroll
    for (int k = 0; k < 2; ++k) {
        gload16(ApL + k * 8 * DMODEL, &As[0][w * 16 + k * 8][0]);
        gload16(BpL + k * 8 * DMODEL, &Bs[0][w * 16 + k * 8][0]);
    }
    __syncthreads();

    for (int it = 0; it < 16; ++it) {
        const int cur = it & 1;
        if (it + 1 < 16) {
            const int kk = (it + 1) * 64;
#pragma unroll
            for (int k = 0; k < 2; ++k) {
                gload16(ApL + k * 8 * DMODEL + kk, &As[cur ^ 1][w * 16 + k * 8][0]);
                gload16(BpL + k * 8 * DMODEL + kk, &Bs[cur ^ 1][w * 16 + k * 8][0]);
            }
        }
#pragma unroll
        for (int c = 0; c < 2; ++c) {
            short8 af[2], bf[2];
#pragma unroll
            for (int i = 0; i < 2; ++i)
                af[i] = *(const short8*)&As[cur][wm + i * 16 + l15][((4 * c + quad) ^ rx) * 8];
#pragma unroll
            for (int j = 0; j < 2; ++j)
                bf[j] = *(const short8*)&Bs[cur][wn + j * 16 + l15][((4 * c + quad) ^ rx) * 8];
#pragma unroll
            for (int i = 0; i < 2; ++i)
#pragma unroll
                for (int j = 0; j < 2; ++j)
                    acc[i][j] = __builtin_amdgcn_mfma_f32_16x16x32_bf16(af[i], bf[j], acc[i][j], 0, 0, 0);
        }
        __syncthreads();   // drains gload (next buf ready) + all reads of cur done
    }

#pragma unroll
    for (int i = 0; i < 2; ++i)
#pragma unroll
        for (int j = 0; j < 2; ++j) {
            const int cl = nl0 + wn + j * 16 + l15;
            if (ep == 1) {
#pragma unroll
                for (int r4 = 0; r4 < 4; ++r4) {
                    const int r = m0 + wm + i * 16 + quad * 4 + r4;
                    float own = acc[i][j][r4];
                    float other = __shfl_xor(own, 1, 64);
                    const int p = (cl & 63) >> 1;
                    const float c = fc[r * 32 + p] * epsc, s = fs[r * 32 + p] * epsc;
                    float outv = ((cl & 1) == 0) ? (own * c - other * s)
                                                 : (other * s + own * c);
                    dbf[(size_t)r * dstride + cl] = f2bf(outv);
                }
            } else {
                // packed 4-key store: r4=0..3 are consecutive jv in FV2
                const int rb = m0 + wm + i * 16 + quad * 4;
                const int g = cl >> 6, d = cl & 63;
                const int d2 = d >> 5, dl = d & 31;
                const int keyblk = rb >> 7, kg = (rb >> 5) & 3;
                const int kst = (rb >> 4) & 1, hb = (rb >> 3) & 1, jv = rb & 7;
                size_t idx = ((((((size_t)(g * 16 + keyblk) * 4 + kg) * 2 + kst) * 2 + d2)
                               * 2 + hb) * 32 + dl) * 8 + jv;
                uint2 pk;
                pk.x = pack2(acc[i][j][0], acc[i][j][1]);
                pk.y = pack2(acc[i][j][2], acc[i][j][3]);
                *(uint2*)(FVout + idx) = pk;
            }
        }
}

// ---------------------------------------------------------------------------
// Output GEMM: same gload_lds + swizzle structure, tile 64x64, fp32 out.
// grid (32,16) = 512 blocks -> 2 blocks/CU even.
// ---------------------------------------------------------------------------
__global__ __launch_bounds__(256, 2) void gemm_out(
    const u16* __restrict__ A, const u16* __restrict__ Bt, float* __restrict__ Dout)
{
    __shared__ u16 As[2][64][64];
    __shared__ u16 Bs[2][64][64];
    const int t = threadIdx.x;
    const int m0 = blockIdx.x * 64;
    const int nl0 = blockIdx.y * 64;

    const int w = t >> 6, lane = t & 63;
    const int quad = lane >> 4, l15 = lane & 15;
    const int wm = (w >> 1) * 32, wn = (w & 1) * 32;
    const int rx = l15 & 7;

    const int sro = w * 16 + (lane >> 3);
    const int sco = ((lane & 7) ^ (lane >> 3)) * 8;
    const u16* ApL = A + (size_t)(m0 + sro) * DMODEL + sco;
    const u16* BpL = Bt + (size_t)(nl0 + sro) * DMODEL + sco;

    f32x4 acc[2][2];
#pragma unroll
    for (int i = 0; i < 2; ++i)
#pragma unroll
        for (int j = 0; j < 2; ++j) acc[i][j] = {0.f, 0.f, 0.f, 0.f};

#pragma unroll
    for (int k = 0; k < 2; ++k) {
        gload16(ApL + k * 8 * DMODEL, &As[0][w * 16 + k * 8][0]);
        gload16(BpL + k * 8 * DMODEL, &Bs[0][w * 16 + k * 8][0]);
    }
    __syncthreads();

    for (int it = 0; it < 16; ++it) {
        const int cur = it & 1;
        if (it + 1 < 16) {
            const int kk = (it + 1) * 64;
#pragma unroll
            for (int k = 0; k < 2; ++k) {
                gload16(ApL + k * 8 * DMODEL + kk, &As[cur ^ 1][w * 16 + k * 8][0]);
                gload16(BpL + k * 8 * DMODEL + kk, &Bs[cur ^ 1][w * 16 + k * 8][0]);
            }
        }
#pragma unroll
        for (int c = 0; c < 2; ++c) {
            short8 af[2], bf[2];
#pragma unroll
            for (int i = 0; i < 2; ++i)
                af[i] = *(const short8*)&As[cur][wm + i * 16 + l15][((4 * c + quad) ^ rx) * 8];
#pragma unroll
            for (int j = 0; j < 2; ++j)
                bf[j] = *(const short8*)&Bs[cur][wn + j * 16 + l15][((4 * c + quad) ^ rx) * 8];
#pragma unroll
            for (int i = 0; i < 2; ++i)
#pragma unroll
                for (int j = 0; j < 2; ++j)
                    acc[i][j] = __builtin_amdgcn_mfma_f32_16x16x32_bf16(af[i], bf[j], acc[i][j], 0, 0, 0);
        }
        __syncthreads();
    }

#pragma unroll
    for (int i = 0; i < 2; ++i)
#pragma unroll
        for (int j = 0; j < 2; ++j) {
            const int cl = nl0 + wn + j * 16 + l15;
#pragma unroll
            for (int r4 = 0; r4 < 4; ++r4) {
                const int r = m0 + wm + i * 16 + quad * 4 + r4;
                Dout[(size_t)r * 1024 + cl] = acc[i][j][r4];
            }
        }
}

// ---------------------------------------------------------------------------
// MFMA flash attention, 32x32x16, IN-BLOCK key-split.
// Grid (32 qtiles, 16 heads) = 512 blocks, 4 waves, 2 blocks/CU.
// P now assembled IN REGISTERS via v_permlane32_swap_b32 (T12):
// S^T layout gives lane q keys {(r&3)+8(r>>2)}+4hi; lane q^32 holds the
// complementary runs. swap(pk(p0,p1), pk(p4,p5)) -> {w0,w2} of the PV
// A-fragment; no P LDS round-trip (4 ds_write + 2 ds_read + lgkm removed).
// Both kg V-fragments prefetched at round start; setprio(1) around MFMA.
// l via ones-column MFMA. Partials merged through LDS (Ks reused), bf16 out.
// ---------------------------------------------------------------------------
__global__ __launch_bounds__(256, 2) void attn(
    const u16* __restrict__ Qb, const u16* __restrict__ Kb,
    const u16* __restrict__ FV, u16* __restrict__ Ob)
{
    __shared__ u16 Ks[2][2][64][72];  // [buf][khalf][key][d], row 144B conflict-free

    const int t = threadIdx.x;
    const int n0 = blockIdx.x * 64;
    const int h = blockIdx.y, kvh = h >> 2;
    const int w = t >> 6, lane = t & 63;
    const int hi = lane >> 5, l31 = lane & 31;
    const int qgrp = w & 1, khalf = w >> 1;
    const int srow = t >> 1, ssel = (t & 1) * 32;   // staging: 2x64 rows x 64d
    const int khalf_s = srow >> 6, klocal = srow & 63;

    const short8 ones = {(short)0x3F80, (short)0x3F80, (short)0x3F80, (short)0x3F80,
                         (short)0x3F80, (short)0x3F80, (short)0x3F80, (short)0x3F80};

    // Q B-frags: B[k=d][n=q], q = n0 + qgrp*32 + l31, d = s*16 + hi*8 + j
    const u16* qp = Qb + (size_t)(n0 + qgrp * 32 + l31) * (NH * HDIM) + h * HDIM + hi * 8;
    short8 qf[4];
#pragma unroll
    for (int s = 0; s < 4; ++s) qf[s] = *(const short8*)(qp + s * 16);

    const u16* kbase = Kb + (size_t)(khalf_s * 1024 + klocal) * (NKV * HDIM) + kvh * HDIM + ssel;
    const u16* fvb = FV + ((size_t)kvh * 16 * 8192) + (size_t)lane * 8;

    f32x16 o[2], o_l;
#pragma unroll
    for (int d2 = 0; d2 < 2; ++d2)
#pragma unroll
        for (int r = 0; r < 16; ++r) o[d2][r] = 0.f;
#pragma unroll
    for (int r = 0; r < 16; ++r) o_l[r] = 0.f;

    // prologue: first 64 keys of each half -> buf 0
#pragma unroll
    for (int c = 0; c < 4; ++c)
        *(uint4*)&Ks[0][khalf_s][klocal][ssel + c * 8] = *(const uint4*)(kbase + c * 8);
    __syncthreads();

    for (int rd = 0; rd < 16; ++rd) {
        const int cur = rd & 1, nxt = cur ^ 1;
        const int rdn = (rd + 1) & 15;            // wrap: dead store on last round
        uint4 kr[4];
#pragma unroll
        for (int c = 0; c < 4; ++c)
            kr[c] = *(const uint4*)(kbase + (size_t)(rdn * 64) * (NKV * HDIM) + c * 8);

        // ---- prefetch BOTH kg's V-fragments for this round ----
        short8 vf[2][2][2];   // [kg][kstep][d2] -- fully unrolled, static idx
#pragma unroll
        for (int kg = 0; kg < 2; ++kg) {
            const int kg_global = khalf * 32 + rd * 2 + kg;
            const int keyblk = kg_global >> 2, kgi = kg_global & 3;
#pragma unroll
            for (int s = 0; s < 2; ++s)
#pragma unroll
                for (int d2 = 0; d2 < 2; ++d2)
                    vf[kg][s][d2] = *(const short8*)(fvb +
                        ((((size_t)keyblk * 4 + kgi) * 2 + s) * 2 + d2) * 512);
        }

#pragma unroll
        for (int kg = 0; kg < 2; ++kg) {
            // ---- S^T = K Q^T over d=64 (4 ksteps of 16) ----
            f32x16 sa;
#pragma unroll
            for (int r = 0; r < 16; ++r) sa[r] = 0.f;
            __builtin_amdgcn_s_setprio(1);
#pragma unroll
            for (int s = 0; s < 4; ++s) {
                short8 kf = *(const short8*)&Ks[cur][khalf][kg * 32 + l31][s * 16 + hi * 8];
                sa = __builtin_amdgcn_mfma_f32_32x32x16_bf16(kf, qf[s], sa, 0, 0, 0);
            }
            __builtin_amdgcn_s_setprio(0);
            // ---- p = exp2(s); PV A-frags assembled in-register ----
            float p[16];
#pragma unroll
            for (int r = 0; r < 16; ++r) p[r] = __builtin_amdgcn_exp2f(sa[r]);
            const u32 A0 = pack2t(p[0],  p[1]);
            const u32 B0 = pack2t(p[2],  p[3]);
            const u32 C0 = pack2t(p[4],  p[5]);
            const u32 D0 = pack2t(p[6],  p[7]);
            const u32 E0 = pack2t(p[8],  p[9]);
            const u32 F0 = pack2t(p[10], p[11]);
            const u32 G0 = pack2t(p[12], p[13]);
            const u32 H0 = pack2t(p[14], p[15]);
            i32x2 X = __builtin_amdgcn_permlane32_swap((int)A0, (int)C0, false, false);
            i32x2 Y = __builtin_amdgcn_permlane32_swap((int)B0, (int)D0, false, false);
            i32x2 Z = __builtin_amdgcn_permlane32_swap((int)E0, (int)G0, false, false);
            i32x2 U = __builtin_amdgcn_permlane32_swap((int)F0, (int)H0, false, false);
            u32x4 t0 = {(u32)X.x, (u32)Y.x, (u32)X.y, (u32)Y.y};
            u32x4 t1 = {(u32)Z.x, (u32)U.x, (u32)Z.y, (u32)U.y};
            const short8 ap0 = __builtin_bit_cast(short8, t0);
            const short8 ap1 = __builtin_bit_cast(short8, t1);
            // ---- O += P V ; l += P 1 (row-sum on the matrix pipe) ----
            __builtin_amdgcn_s_setprio(1);
#pragma unroll
            for (int d2 = 0; d2 < 2; ++d2) {
                o[d2] = __builtin_amdgcn_mfma_f32_32x32x16_bf16(ap0, vf[kg][0][d2], o[d2], 0, 0, 0);
                o[d2] = __builtin_amdgcn_mfma_f32_32x32x16_bf16(ap1, vf[kg][1][d2], o[d2], 0, 0, 0);
            }
            o_l = __builtin_amdgcn_mfma_f32_32x32x16_bf16(ap0, ones, o_l, 0, 0, 0);
            o_l = __builtin_amdgcn_mfma_f32_32x32x16_bf16(ap1, ones, o_l, 0, 0, 0);
            __builtin_amdgcn_s_setprio(0);
        }
        // ---- stage next 64-key tiles (both halves); single barrier ----
#pragma unroll
        for (int c = 0; c < 4; ++c)
            *(uint4*)&Ks[nxt][khalf_s][klocal][ssel + c * 8] = kr[c];
        __syncthreads();
    }

    // ---- merge key halves through LDS (reuse Ks) and write bf16 ----
    float* Xf = (float*)&Ks[0][0][0][0];   // Ox[2][32][64] (4096 f32) + Lx[64]
    if (khalf == 1) {
#pragma unroll
        for (int d2 = 0; d2 < 2; ++d2)
#pragma unroll
            for (int r = 0; r < 16; ++r) {
                const int q32 = (r & 3) + 8 * (r >> 2) + 4 * hi;
                Xf[qgrp * 2048 + q32 * 64 + d2 * 32 + l31] = o[d2][r];
            }
        if (l31 == 0) {
#pragma unroll
            for (int r = 0; r < 16; ++r) {
                const int q32 = (r & 3) + 8 * (r >> 2) + 4 * hi;
                Xf[4096 + qgrp * 32 + q32] = o_l[r];
            }
        }
    }
    __syncthreads();
    if (khalf == 0) {
        float linv[16];
#pragma unroll
        for (int r = 0; r < 16; ++r) {
            const int q32 = (r & 3) + 8 * (r >> 2) + 4 * hi;
            linv[r] = 1.f / (o_l[r] + Xf[4096 + qgrp * 32 + q32]);
        }
#pragma unroll
        for (int d2 = 0; d2 < 2; ++d2)
#pragma unroll
            for (int r = 0; r < 16; ++r) {
                const int q32 = (r & 3) + 8 * (r >> 2) + 4 * hi;
                const float val = o[d2][r] + Xf[qgrp * 2048 + q32 * 64 + d2 * 32 + l31];
                const int qrow = n0 + qgrp * 32 + q32;
                Ob[(size_t)qrow * (NH * HDIM) + h * HDIM + d2 * 32 + l31] = f2bf(val * linv[r]);
            }
    }
}

// ---------------------------------------------------------------------------
extern "C" void kernel_launch(void* const* d_in, const int* in_sizes, int n_in,
                              void* d_out, int out_size, void* d_ws, size_t ws_size,
                              hipStream_t stream) {
    const float* x  = (const float*)d_in[0];
    const float* fc = (const float*)d_in[1];
    const float* fs = (const float*)d_in[2];
    const float* Wq = (const float*)d_in[3];
    const float* Wk = (const float*)d_in[4];
    const float* Wv = (const float*)d_in[5];
    const float* Wo = (const float*)d_in[6];
    float* out = (float*)d_out;

    u16* ws  = (u16*)d_ws;
    u16* xb  = ws;                         // 2048*1024
    u16* Wqt = xb  + (size_t)2048 * 1024;  // 1024*1024
    u16* Wkt = Wqt + (size_t)1024 * 1024;  // 256*1024
    u16* Wvt = Wkt + (size_t)256 * 1024;   // 256*1024
    u16* Wot = Wvt + (size_t)256 * 1024;   // 1024*1024
    u16* qb  = Wot + (size_t)1024 * 1024;  // 2048*1024
    u16* kb  = qb  + (size_t)2048 * 1024;  // 2048*256
    u16* fv  = kb  + (size_t)2048 * 256;   // 256*2048 (fragment-packed V, 32-wide)
    u16* aob = fv  + (size_t)256 * 2048;   // 2048*1024

    prep<<<dim3(16, 16, 5), dim3(256), 0, stream>>>(Wq, Wk, Wv, Wo, x,
                                                    Wqt, Wkt, Wvt, Wot, xb);
    gemm_qkv<<<dim3(32, 24), dim3(256), 0, stream>>>(xb, Wqt, Wkt, Wvt,
                                                     qb, kb, fv, fc, fs);
    attn<<<dim3(32, 16), dim3(256), 0, stream>>>(qb, kb, fv, aob);
    gemm_out<<<dim3(32, 16), dim3(256), 0, stream>>>(aob, Wot, out);
}

// Round 9
// 128.673 us; speedup vs baseline: 2.7254x; 1.0580x over previous
//
#include <hip/hip_runtime.h>

#define N_TOK 2048
#define DMODEL 1024
#define NH 16
#define NKV 4
#define HDIM 64
#define SCALE_LOG2E 0.1803368801111204f  // (1/8) * log2(e)

typedef __attribute__((ext_vector_type(8))) short short8;
typedef __attribute__((ext_vector_type(4))) float f32x4;
typedef __attribute__((ext_vector_type(16))) float f32x16;
typedef __attribute__((ext_vector_type(2))) int i32x2;
typedef __attribute__((ext_vector_type(4))) unsigned int u32x4;
typedef unsigned short u16;
typedef unsigned int u32;

__device__ __forceinline__ u16 f2bf(float x) {
    u32 u = __float_as_uint(x);
    u += 0x7FFF + ((u >> 16) & 1);   // round-to-nearest-even
    return (u16)(u >> 16);
}
__device__ __forceinline__ u32 pack2(float a, float b) {
    return (u32)f2bf(a) | ((u32)f2bf(b) << 16);
}
// pack high halves (truncating bf16) of two floats: [bf(a) | bf(b)<<16]
__device__ __forceinline__ u32 pack2t(float a, float b) {
    return __builtin_amdgcn_perm(__float_as_uint(b), __float_as_uint(a), 0x07060302u);
}

// async global->LDS, 16B/lane: HW writes lds_base + lane*16 (wave-uniform base).
__device__ __forceinline__ void gload16(const u16* g, u16* l) {
    __builtin_amdgcn_global_load_lds(
        (const __attribute__((address_space(1))) unsigned int*)g,
        (__attribute__((address_space(3))) unsigned int*)l, 16, 0, 0);
}

// ---------------------------------------------------------------------------
// prep: z=0..3 transpose W (K x NC) -> Wt (NC x K) bf16; z=4 convert x -> bf16
// ---------------------------------------------------------------------------
__global__ __launch_bounds__(256) void prep(
    const float* __restrict__ Wq, const float* __restrict__ Wk,
    const float* __restrict__ Wv, const float* __restrict__ Wo,
    const float* __restrict__ x,
    u16* __restrict__ Wqt, u16* __restrict__ Wkt, u16* __restrict__ Wvt,
    u16* __restrict__ Wot, u16* __restrict__ xb)
{
    const int z = blockIdx.z;
    const int t = threadIdx.x;
    if (z == 4) {
        size_t base = ((size_t)(blockIdx.y * 16 + blockIdx.x)) * 8192;
#pragma unroll
        for (int i = 0; i < 8; ++i) {
            float4 v = *(const float4*)(x + base + i * 1024 + t * 4);
            uint2 p; p.x = pack2(v.x, v.y); p.y = pack2(v.z, v.w);
            *(uint2*)(xb + base + i * 1024 + t * 4) = p;
        }
        return;
    }
    const float* W; u16* Wt; int NC;
    if      (z == 0) { W = Wq; Wt = Wqt; NC = 1024; }
    else if (z == 1) { W = Wk; Wt = Wkt; NC = 256; }
    else if (z == 2) { W = Wv; Wt = Wvt; NC = 256; }
    else             { W = Wo; Wt = Wot; NC = 1024; }
    const int n0 = blockIdx.x * 64;
    if (n0 >= NC) return;
    const int k0 = blockIdx.y * 64;
    __shared__ float T[64][68];
    const int row = t >> 2, cs = (t & 3) * 16;
#pragma unroll
    for (int i = 0; i < 4; ++i)
        *(float4*)&T[row][cs + i * 4] =
            *(const float4*)(W + (size_t)(k0 + row) * NC + n0 + cs + i * 4);
    __syncthreads();
    const int nl = t >> 2, ks = (t & 3) * 16;
    u32 pk[8];
#pragma unroll
    for (int i = 0; i < 8; ++i)
        pk[i] = pack2(T[ks + 2 * i][nl], T[ks + 2 * i + 1][nl]);
    u16* dst = Wt + (size_t)(n0 + nl) * DMODEL + k0 + ks;
    uint4 w0; w0.x = pk[0]; w0.y = pk[1]; w0.z = pk[2]; w0.w = pk[3];
    uint4 w1; w1.x = pk[4]; w1.y = pk[5]; w1.z = pk[6]; w1.w = pk[7];
    *(uint4*)(dst) = w0;
    *(uint4*)(dst + 8) = w1;
}

// ---------------------------------------------------------------------------
// QKV GEMM: tile 64x64, BK=64, gload_lds staging, 3-BUFFER RING with counted
// vmcnt (T4): prefetch distance 2; at each barrier only the newest 4 loads
// (tile it+2) stay in flight -- never vmcnt(0) in the main loop. Raw
// s_barrier (no compiler drain). Both-sides XOR swizzle. 4 waves of 32x32.
// grid (32,24) = 768 blocks -> 3 blocks/CU (LDS 48 KB).
// by<16 -> Q (rope, x SCALE_LOG2E); 16..19 -> K (rope); 20..23 -> V in FV2:
//   FV2[((((((g*16+keyblk)*4+kg)*2+kstep)*2+dgrp)*2+hi)*32+dl)*8+j]
//     = V[key = keyblk*128 + kg*32 + kstep*16 + hi*8 + j][d = dgrp*32 + dl]
// ---------------------------------------------------------------------------
__global__ __launch_bounds__(256, 3) void gemm_qkv(
    const u16* __restrict__ A,
    const u16* __restrict__ B0, const u16* __restrict__ B1, const u16* __restrict__ B2,
    u16* __restrict__ D0, u16* __restrict__ D1, u16* __restrict__ FVout,
    const float* __restrict__ fc, const float* __restrict__ fs)
{
    __shared__ u16 As[3][64][64];   // linear: required by global_load_lds
    __shared__ u16 Bs[3][64][64];
    const int t = threadIdx.x;
    const int m0 = blockIdx.x * 64;
    const int by = blockIdx.y;

    const u16* Bt; int nl0, ep;           // ep: 1 rope bf16, 2 FV2
    u16* dbf = nullptr; int dstride = 0; float epsc = 1.f;
    if (by < 16)      { Bt = B0; nl0 = by * 64;        dbf = D0; ep = 1; dstride = 1024;
                        epsc = SCALE_LOG2E; }
    else if (by < 20) { Bt = B1; nl0 = (by - 16) * 64; dbf = D1; ep = 1; dstride = 256; }
    else              { Bt = B2; nl0 = (by - 20) * 64; ep = 2; }

    const int w = t >> 6, lane = t & 63;
    const int quad = lane >> 4, l15 = lane & 15;
    const int wm = (w >> 1) * 32, wn = (w & 1) * 32;
    const int rx = l15 & 7;                         // read-side swizzle key

    // staging: wave w covers tile rows [w*16, w*16+16), 2 instrs x 8 rows each
    const int sro = w * 16 + (lane >> 3);           // per-lane staged row
    const int sco = ((lane & 7) ^ (lane >> 3)) * 8; // pre-swizzled source col
    const u16* ApL = A + (size_t)(m0 + sro) * DMODEL + sco;
    const u16* BpL = Bt + (size_t)(nl0 + sro) * DMODEL + sco;

    f32x4 acc[2][2];
#pragma unroll
    for (int i = 0; i < 2; ++i)
#pragma unroll
        for (int j = 0; j < 2; ++j) acc[i][j] = {0.f, 0.f, 0.f, 0.f};

    // prologue: tile 0 -> buf0, tile 1 -> buf1; wait tile0 (4 newest in flight)
#pragma unroll
    for (int k = 0; k < 2; ++k) {
        gload16(ApL + k * 8 * DMODEL, &As[0][w * 16 + k * 8][0]);
        gload16(BpL + k * 8 * DMODEL, &Bs[0][w * 16 + k * 8][0]);
    }
#pragma unroll
    for (int k = 0; k < 2; ++k) {
        gload16(ApL + k * 8 * DMODEL + 64, &As[1][w * 16 + k * 8][0]);
        gload16(BpL + k * 8 * DMODEL + 64, &Bs[1][w * 16 + k * 8][0]);
    }
    asm volatile("s_waitcnt vmcnt(4)" ::: "memory");
    __builtin_amdgcn_sched_barrier(0);
    __builtin_amdgcn_s_barrier();

    int cb = 0, nb = 1, pb = 2;    // current / next / prefetch buffer ids
    for (int it = 0; it < 16; ++it) {
        if (it + 2 < 16) {
            const int kk = (it + 2) * 64;
#pragma unroll
            for (int k = 0; k < 2; ++k) {
                gload16(ApL + k * 8 * DMODEL + kk, &As[pb][w * 16 + k * 8][0]);
                gload16(BpL + k * 8 * DMODEL + kk, &Bs[pb][w * 16 + k * 8][0]);
            }
        }
#pragma unroll
        for (int c = 0; c < 2; ++c) {
            short8 af[2], bf[2];
#pragma unroll
            for (int i = 0; i < 2; ++i)
                af[i] = *(const short8*)&As[cb][wm + i * 16 + l15][((4 * c + quad) ^ rx) * 8];
#pragma unroll
            for (int j = 0; j < 2; ++j)
                bf[j] = *(const short8*)&Bs[cb][wn + j * 16 + l15][((4 * c + quad) ^ rx) * 8];
#pragma unroll
            for (int i = 0; i < 2; ++i)
#pragma unroll
                for (int j = 0; j < 2; ++j)
                    acc[i][j] = __builtin_amdgcn_mfma_f32_16x16x32_bf16(af[i], bf[j], acc[i][j], 0, 0, 0);
        }
        // next tile (issued 2 iters back) must be drained; newest 4 may fly on
        if (it + 2 < 16) asm volatile("s_waitcnt vmcnt(4)" ::: "memory");
        else             asm volatile("s_waitcnt vmcnt(0)" ::: "memory");
        __builtin_amdgcn_sched_barrier(0);
        __builtin_amdgcn_s_barrier();
        const int tmp = cb; cb = nb; nb = pb; pb = tmp;
    }

#pragma unroll
    for (int i = 0; i < 2; ++i)
#pragma unroll
        for (int j = 0; j < 2; ++j) {
            const int cl = nl0 + wn + j * 16 + l15;
            if (ep == 1) {
#pragma unroll
                for (int r4 = 0; r4 < 4; ++r4) {
                    const int r = m0 + wm + i * 16 + quad * 4 + r4;
                    float own = acc[i][j][r4];
                    float other = __shfl_xor(own, 1, 64);
                    const int p = (cl & 63) >> 1;
                    const float c = fc[r * 32 + p] * epsc, s = fs[r * 32 + p] * epsc;
                    float outv = ((cl & 1) == 0) ? (own * c - other * s)
                                                 : (other * s + own * c);
                    dbf[(size_t)r * dstride + cl] = f2bf(outv);
                }
            } else {
                // packed 4-key store: r4=0..3 are consecutive jv in FV2
                const int rb = m0 + wm + i * 16 + quad * 4;
                const int g = cl >> 6, d = cl & 63;
                const int d2 = d >> 5, dl = d & 31;
                const int keyblk = rb >> 7, kg = (rb >> 5) & 3;
                const int kst = (rb >> 4) & 1, hb = (rb >> 3) & 1, jv = rb & 7;
                size_t idx = ((((((size_t)(g * 16 + keyblk) * 4 + kg) * 2 + kst) * 2 + d2)
                               * 2 + hb) * 32 + dl) * 8 + jv;
                uint2 pk;
                pk.x = pack2(acc[i][j][0], acc[i][j][1]);
                pk.y = pack2(acc[i][j][2], acc[i][j][3]);
                *(uint2*)(FVout + idx) = pk;
            }
        }
}

// ---------------------------------------------------------------------------
// Output GEMM: same 3-buffer counted-vmcnt structure, tile 64x64, fp32 out.
// grid (32,16) = 512 blocks -> 2 blocks/CU even.
// ---------------------------------------------------------------------------
__global__ __launch_bounds__(256, 2) void gemm_out(
    const u16* __restrict__ A, const u16* __restrict__ Bt, float* __restrict__ Dout)
{
    __shared__ u16 As[3][64][64];
    __shared__ u16 Bs[3][64][64];
    const int t = threadIdx.x;
    const int m0 = blockIdx.x * 64;
    const int nl0 = blockIdx.y * 64;

    const int w = t >> 6, lane = t & 63;
    const int quad = lane >> 4, l15 = lane & 15;
    const int wm = (w >> 1) * 32, wn = (w & 1) * 32;
    const int rx = l15 & 7;

    const int sro = w * 16 + (lane >> 3);
    const int sco = ((lane & 7) ^ (lane >> 3)) * 8;
    const u16* ApL = A + (size_t)(m0 + sro) * DMODEL + sco;
    const u16* BpL = Bt + (size_t)(nl0 + sro) * DMODEL + sco;

    f32x4 acc[2][2];
#pragma unroll
    for (int i = 0; i < 2; ++i)
#pragma unroll
        for (int j = 0; j < 2; ++j) acc[i][j] = {0.f, 0.f, 0.f, 0.f};

#pragma unroll
    for (int k = 0; k < 2; ++k) {
        gload16(ApL + k * 8 * DMODEL, &As[0][w * 16 + k * 8][0]);
        gload16(BpL + k * 8 * DMODEL, &Bs[0][w * 16 + k * 8][0]);
    }
#pragma unroll
    for (int k = 0; k < 2; ++k) {
        gload16(ApL + k * 8 * DMODEL + 64, &As[1][w * 16 + k * 8][0]);
        gload16(BpL + k * 8 * DMODEL + 64, &Bs[1][w * 16 + k * 8][0]);
    }
    asm volatile("s_waitcnt vmcnt(4)" ::: "memory");
    __builtin_amdgcn_sched_barrier(0);
    __builtin_amdgcn_s_barrier();

    int cb = 0, nb = 1, pb = 2;
    for (int it = 0; it < 16; ++it) {
        if (it + 2 < 16) {
            const int kk = (it + 2) * 64;
#pragma unroll
            for (int k = 0; k < 2; ++k) {
                gload16(ApL + k * 8 * DMODEL + kk, &As[pb][w * 16 + k * 8][0]);
                gload16(BpL + k * 8 * DMODEL + kk, &Bs[pb][w * 16 + k * 8][0]);
            }
        }
#pragma unroll
        for (int c = 0; c < 2; ++c) {
            short8 af[2], bf[2];
#pragma unroll
            for (int i = 0; i < 2; ++i)
                af[i] = *(const short8*)&As[cb][wm + i * 16 + l15][((4 * c + quad) ^ rx) * 8];
#pragma unroll
            for (int j = 0; j < 2; ++j)
                bf[j] = *(const short8*)&Bs[cb][wn + j * 16 + l15][((4 * c + quad) ^ rx) * 8];
#pragma unroll
            for (int i = 0; i < 2; ++i)
#pragma unroll
                for (int j = 0; j < 2; ++j)
                    acc[i][j] = __builtin_amdgcn_mfma_f32_16x16x32_bf16(af[i], bf[j], acc[i][j], 0, 0, 0);
        }
        if (it + 2 < 16) asm volatile("s_waitcnt vmcnt(4)" ::: "memory");
        else             asm volatile("s_waitcnt vmcnt(0)" ::: "memory");
        __builtin_amdgcn_sched_barrier(0);
        __builtin_amdgcn_s_barrier();
        const int tmp = cb; cb = nb; nb = pb; pb = tmp;
    }

#pragma unroll
    for (int i = 0; i < 2; ++i)
#pragma unroll
        for (int j = 0; j < 2; ++j) {
            const int cl = nl0 + wn + j * 16 + l15;
#pragma unroll
            for (int r4 = 0; r4 < 4; ++r4) {
                const int r = m0 + wm + i * 16 + quad * 4 + r4;
                Dout[(size_t)r * 1024 + cl] = acc[i][j][r4];
            }
        }
}

// ---------------------------------------------------------------------------
// MFMA flash attention, 32x32x16, IN-BLOCK key-split.
// Grid (32 qtiles, 16 heads) = 512 blocks, 4 waves, 2 blocks/CU.
// P assembled IN REGISTERS via v_permlane32_swap_b32 (T12); no P LDS trip.
// Both kg V-fragments prefetched at round start; setprio(1) around MFMA.
// l via ones-column MFMA. Partials merged through LDS (Ks reused), bf16 out.
// ---------------------------------------------------------------------------
__global__ __launch_bounds__(256, 2) void attn(
    const u16* __restrict__ Qb, const u16* __restrict__ Kb,
    const u16* __restrict__ FV, u16* __restrict__ Ob)
{
    __shared__ u16 Ks[2][2][64][72];  // [buf][khalf][key][d], row 144B conflict-free

    const int t = threadIdx.x;
    const int n0 = blockIdx.x * 64;
    const int h = blockIdx.y, kvh = h >> 2;
    const int w = t >> 6, lane = t & 63;
    const int hi = lane >> 5, l31 = lane & 31;
    const int qgrp = w & 1, khalf = w >> 1;
    const int srow = t >> 1, ssel = (t & 1) * 32;   // staging: 2x64 rows x 64d
    const int khalf_s = srow >> 6, klocal = srow & 63;

    const short8 ones = {(short)0x3F80, (short)0x3F80, (short)0x3F80, (short)0x3F80,
                         (short)0x3F80, (short)0x3F80, (short)0x3F80, (short)0x3F80};

    // Q B-frags: B[k=d][n=q], q = n0 + qgrp*32 + l31, d = s*16 + hi*8 + j
    const u16* qp = Qb + (size_t)(n0 + qgrp * 32 + l31) * (NH * HDIM) + h * HDIM + hi * 8;
    short8 qf[4];
#pragma unroll
    for (int s = 0; s < 4; ++s) qf[s] = *(const short8*)(qp + s * 16);

    const u16* kbase = Kb + (size_t)(khalf_s * 1024 + klocal) * (NKV * HDIM) + kvh * HDIM + ssel;
    const u16* fvb = FV + ((size_t)kvh * 16 * 8192) + (size_t)lane * 8;

    f32x16 o[2], o_l;
#pragma unroll
    for (int d2 = 0; d2 < 2; ++d2)
#pragma unroll
        for (int r = 0; r < 16; ++r) o[d2][r] = 0.f;
#pragma unroll
    for (int r = 0; r < 16; ++r) o_l[r] = 0.f;

    // prologue: first 64 keys of each half -> buf 0
#pragma unroll
    for (int c = 0; c < 4; ++c)
        *(uint4*)&Ks[0][khalf_s][klocal][ssel + c * 8] = *(const uint4*)(kbase + c * 8);
    __syncthreads();

    for (int rd = 0; rd < 16; ++rd) {
        const int cur = rd & 1, nxt = cur ^ 1;
        const int rdn = (rd + 1) & 15;            // wrap: dead store on last round
        uint4 kr[4];
#pragma unroll
        for (int c = 0; c < 4; ++c)
            kr[c] = *(const uint4*)(kbase + (size_t)(rdn * 64) * (NKV * HDIM) + c * 8);

        // ---- prefetch BOTH kg's V-fragments for this round ----
        short8 vf[2][2][2];   // [kg][kstep][d2] -- fully unrolled, static idx
#pragma unroll
        for (int kg = 0; kg < 2; ++kg) {
            const int kg_global = khalf * 32 + rd * 2 + kg;
            const int keyblk = kg_global >> 2, kgi = kg_global & 3;
#pragma unroll
            for (int s = 0; s < 2; ++s)
#pragma unroll
                for (int d2 = 0; d2 < 2; ++d2)
                    vf[kg][s][d2] = *(const short8*)(fvb +
                        ((((size_t)keyblk * 4 + kgi) * 2 + s) * 2 + d2) * 512);
        }

#pragma unroll
        for (int kg = 0; kg < 2; ++kg) {
            // ---- S^T = K Q^T over d=64 (4 ksteps of 16) ----
            f32x16 sa;
#pragma unroll
            for (int r = 0; r < 16; ++r) sa[r] = 0.f;
            __builtin_amdgcn_s_setprio(1);
#pragma unroll
            for (int s = 0; s < 4; ++s) {
                short8 kf = *(const short8*)&Ks[cur][khalf][kg * 32 + l31][s * 16 + hi * 8];
                sa = __builtin_amdgcn_mfma_f32_32x32x16_bf16(kf, qf[s], sa, 0, 0, 0);
            }
            __builtin_amdgcn_s_setprio(0);
            // ---- p = exp2(s); PV A-frags assembled in-register ----
            float p[16];
#pragma unroll
            for (int r = 0; r < 16; ++r) p[r] = __builtin_amdgcn_exp2f(sa[r]);
            const u32 A0 = pack2t(p[0],  p[1]);
            const u32 B0 = pack2t(p[2],  p[3]);
            const u32 C0 = pack2t(p[4],  p[5]);
            const u32 D0 = pack2t(p[6],  p[7]);
            const u32 E0 = pack2t(p[8],  p[9]);
            const u32 F0 = pack2t(p[10], p[11]);
            const u32 G0 = pack2t(p[12], p[13]);
            const u32 H0 = pack2t(p[14], p[15]);
            i32x2 X = __builtin_amdgcn_permlane32_swap((int)A0, (int)C0, false, false);
            i32x2 Y = __builtin_amdgcn_permlane32_swap((int)B0, (int)D0, false, false);
            i32x2 Z = __builtin_amdgcn_permlane32_swap((int)E0, (int)G0, false, false);
            i32x2 U = __builtin_amdgcn_permlane32_swap((int)F0, (int)H0, false, false);
            u32x4 t0 = {(u32)X.x, (u32)Y.x, (u32)X.y, (u32)Y.y};
            u32x4 t1 = {(u32)Z.x, (u32)U.x, (u32)Z.y, (u32)U.y};
            const short8 ap0 = __builtin_bit_cast(short8, t0);
            const short8 ap1 = __builtin_bit_cast(short8, t1);
            // ---- O += P V ; l += P 1 (row-sum on the matrix pipe) ----
            __builtin_amdgcn_s_setprio(1);
#pragma unroll
            for (int d2 = 0; d2 < 2; ++d2) {
                o[d2] = __builtin_amdgcn_mfma_f32_32x32x16_bf16(ap0, vf[kg][0][d2], o[d2], 0, 0, 0);
                o[d2] = __builtin_amdgcn_mfma_f32_32x32x16_bf16(ap1, vf[kg][1][d2], o[d2], 0, 0, 0);
            }
            o_l = __builtin_amdgcn_mfma_f32_32x32x16_bf16(ap0, ones, o_l, 0, 0, 0);
            o_l = __builtin_amdgcn_mfma_f32_32x32x16_bf16(ap1, ones, o_l, 0, 0, 0);
            __builtin_amdgcn_s_setprio(0);
        }
        // ---- stage next 64-key tiles (both halves); single barrier ----
#pragma unroll
        for (int c = 0; c < 4; ++c)
            *(uint4*)&Ks[nxt][khalf_s][klocal][ssel + c * 8] = kr[c];
        __syncthreads();
    }

    // ---- merge key halves through LDS (reuse Ks) and write bf16 ----
    float* Xf = (float*)&Ks[0][0][0][0];   // Ox[2][32][64] (4096 f32) + Lx[64]
    if (khalf == 1) {
#pragma unroll
        for (int d2 = 0; d2 < 2; ++d2)
#pragma unroll
            for (int r = 0; r < 16; ++r) {
                const int q32 = (r & 3) + 8 * (r >> 2) + 4 * hi;
                Xf[qgrp * 2048 + q32 * 64 + d2 * 32 + l31] = o[d2][r];
            }
        if (l31 == 0) {
#pragma unroll
            for (int r = 0; r < 16; ++r) {
                const int q32 = (r & 3) + 8 * (r >> 2) + 4 * hi;
                Xf[4096 + qgrp * 32 + q32] = o_l[r];
            }
        }
    }
    __syncthreads();
    if (khalf == 0) {
        float linv[16];
#pragma unroll
        for (int r = 0; r < 16; ++r) {
            const int q32 = (r & 3) + 8 * (r >> 2) + 4 * hi;
            linv[r] = 1.f / (o_l[r] + Xf[4096 + qgrp * 32 + q32]);
        }
#pragma unroll
        for (int d2 = 0; d2 < 2; ++d2)
#pragma unroll
            for (int r = 0; r < 16; ++r) {
                const int q32 = (r & 3) + 8 * (r >> 2) + 4 * hi;
                const float val = o[d2][r] + Xf[qgrp * 2048 + q32 * 64 + d2 * 32 + l31];
                const int qrow = n0 + qgrp * 32 + q32;
                Ob[(size_t)qrow * (NH * HDIM) + h * HDIM + d2 * 32 + l31] = f2bf(val * linv[r]);
            }
    }
}

// ---------------------------------------------------------------------------
extern "C" void kernel_launch(void* const* d_in, const int* in_sizes, int n_in,
                              void* d_out, int out_size, void* d_ws, size_t ws_size,
                              hipStream_t stream) {
    const float* x  = (const float*)d_in[0];
    const float* fc = (const float*)d_in[1];
    const float* fs = (const float*)d_in[2];
    const float* Wq = (const float*)d_in[3];
    const float* Wk = (const float*)d_in[4];
    const float* Wv = (const float*)d_in[5];
    const float* Wo = (const float*)d_in[6];
    float* out = (float*)d_out;

    u16* ws  = (u16*)d_ws;
    u16* xb  = ws;                         // 2048*1024
    u16* Wqt = xb  + (size_t)2048 * 1024;  // 1024*1024
    u16* Wkt = Wqt + (size_t)1024 * 1024;  // 256*1024
    u16* Wvt = Wkt + (size_t)256 * 1024;   // 256*1024
    u16* Wot = Wvt + (size_t)256 * 1024;   // 1024*1024
    u16* qb  = Wot + (size_t)1024 * 1024;  // 2048*1024
    u16* kb  = qb  + (size_t)2048 * 1024;  // 2048*256
    u16* fv  = kb  + (size_t)2048 * 256;   // 256*2048 (fragment-packed V, 32-wide)
    u16* aob = fv  + (size_t)256 * 2048;   // 2048*1024

    prep<<<dim3(16, 16, 5), dim3(256), 0, stream>>>(Wq, Wk, Wv, Wo, x,
                                                    Wqt, Wkt, Wvt, Wot, xb);
    gemm_qkv<<<dim3(32, 24), dim3(256), 0, stream>>>(xb, Wqt, Wkt, Wvt,
                                                     qb, kb, fv, fc, fs);
    attn<<<dim3(32, 16), dim3(256), 0, stream>>>(qb, kb, fv, aob);
    gemm_out<<<dim3(32, 16), dim3(256), 0, stream>>>(aob, Wot, out);
}